// Round 2
// baseline (953.770 us; speedup 1.0000x reference)
//
#include <hip/hip_runtime.h>
#include <math.h>

// Problem sizes (fixed by the reference)
#define NB   2
#define CC   256
#define HH   64
#define WW   64
#define NH   8
#define DD   32
#define PQ   4096   // 64*64 queries per image
#define PKV  1024   // 32*32 kv per image
#define WIN  18     // max kv window extent per axis

#define NF (-INFINITY)

// res = dot(qarr[0..31], ptr[0..31]) with 4 partial sums (ILP)
#define DOT32(res, qarr, ptr)                                    \
  {                                                              \
    const float4* _r = reinterpret_cast<const float4*>(ptr);     \
    float _s0 = 0.f, _s1 = 0.f, _s2 = 0.f, _s3 = 0.f;            \
    _Pragma("unroll")                                            \
    for (int _t = 0; _t < 8; ++_t) {                             \
      const float4 _v = _r[_t];                                  \
      _s0 = fmaf(qarr[4 * _t + 0], _v.x, _s0);                   \
      _s1 = fmaf(qarr[4 * _t + 1], _v.y, _s1);                   \
      _s2 = fmaf(qarr[4 * _t + 2], _v.z, _s2);                   \
      _s3 = fmaf(qarr[4 * _t + 3], _v.w, _s3);                   \
    }                                                            \
    res = (_s0 + _s1) + (_s2 + _s3);                             \
  }

// ---------------------------------------------------------------------------
// Transpose the four 256x256 weight matrices: Wt[c][o] = W[o][c]
// ---------------------------------------------------------------------------
__global__ __launch_bounds__(256) void transpose4_kernel(
    const float* __restrict__ a, const float* __restrict__ b,
    const float* __restrict__ c, const float* __restrict__ d,
    float* __restrict__ ta, float* __restrict__ tb,
    float* __restrict__ tc, float* __restrict__ td) {
  const int which = blockIdx.y;
  const float* src = (which == 0) ? a : (which == 1) ? b : (which == 2) ? c : d;
  float* dst = (which == 0) ? ta : (which == 1) ? tb : (which == 2) ? tc : td;
  const int idx = blockIdx.x * 256 + threadIdx.x;   // 65536 total
  const int o = idx >> 8, ch = idx & 255;
  dst[ch * 256 + o] = src[idx];
}

// ---------------------------------------------------------------------------
// Positional features:
//   pf[head][i][k][dd] = (1/sqrt(2)) * sum_f feat(i,k)[f] * FC[head*32+dd][f]
// ---------------------------------------------------------------------------
__global__ __launch_bounds__(256) void posfeat_kernel(
    const float* __restrict__ fcx, const float* __restrict__ fcy,
    float* __restrict__ pfx, float* __restrict__ pfy) {
  const int i = blockIdx.x;
  const int k = blockIdx.y;
  const int which = blockIdx.z;
  const float* FC = which ? fcy : fcx;
  float* OUT = which ? pfy : pfx;
  __shared__ __align__(16) float feat[128];
  const int tid = threadIdx.x;
  if (tid < 64) {
    const float diff = (float)(i - 2 * k);
    const float dm = powf(1000.f, (float)tid * (1.f / 64.f));
    const float aa = diff / dm;
    feat[tid] = sinf(aa);
    feat[tid + 64] = cosf(aa);
  }
  __syncthreads();
  const float4* row4 = reinterpret_cast<const float4*>(FC + tid * 128);
  const float4* f4 = reinterpret_cast<const float4*>(feat);
  float s0 = 0.f, s1 = 0.f, s2 = 0.f, s3 = 0.f;
#pragma unroll
  for (int f = 0; f < 32; ++f) {
    const float4 fv = f4[f];
    const float4 rv = row4[f];
    s0 = fmaf(fv.x, rv.x, s0);
    s1 = fmaf(fv.y, rv.y, s1);
    s2 = fmaf(fv.z, rv.z, s2);
    s3 = fmaf(fv.w, rv.w, s3);
  }
  const float s = ((s0 + s1) + (s2 + s3)) * 0.70710678118654752440f;
  OUT[(((size_t)(tid >> 5) * 64 + i) * 32 + k) * 32 + (tid & 31)] = s;
}

// ---------------------------------------------------------------------------
// QKV projection (unchanged from R1)
// ---------------------------------------------------------------------------
template <int MODE>
__global__ __launch_bounds__(256) void proj_kernel(
    const float* __restrict__ X, const float* __restrict__ WtA,
    const float* __restrict__ WtB, float* __restrict__ outA,
    float* __restrict__ outB) {
  constexpr int P = (MODE == 0) ? PQ : PKV;
  const int n = blockIdx.y;
  const float* Wt = WtA;
  float* out = outA;
  if (MODE == 1 && blockIdx.z == 1) { Wt = WtB; out = outB; }
  const int p0 = blockIdx.x * 32;
  const float* Xn = X + (size_t)n * (CC * PQ);
  __shared__ float xs[256][32];
  const int tid = threadIdx.x;
  {
    const int pl = tid & 31;
    const int c0 = tid >> 5;  // 0..7
    const int p = p0 + pl;
    const int gp = (MODE == 0) ? p : ((p >> 5) * 128 + (p & 31) * 2);
#pragma unroll
    for (int i = 0; i < 32; ++i) {
      const int c = i * 8 + c0;
      xs[c][pl] = Xn[(size_t)c * PQ + gp];
    }
  }
  __syncthreads();
  const int og = tid & 63;   // 64 output groups of 4
  const int pg = tid >> 6;   // 4 pixel groups of 8
  const int o0 = og * 4;
  const int pl0 = pg * 8;
  float acc[4][8];
#pragma unroll
  for (int j = 0; j < 4; ++j)
#pragma unroll
    for (int i = 0; i < 8; ++i) acc[j][i] = 0.f;
#pragma unroll 4
  for (int c = 0; c < 256; ++c) {
    const float4 wv = *reinterpret_cast<const float4*>(Wt + c * 256 + o0);
#pragma unroll
    for (int i = 0; i < 8; ++i) {
      const float xv = xs[c][pl0 + i];
      acc[0][i] = fmaf(wv.x, xv, acc[0][i]);
      acc[1][i] = fmaf(wv.y, xv, acc[1][i]);
      acc[2][i] = fmaf(wv.z, xv, acc[2][i]);
      acc[3][i] = fmaf(wv.w, xv, acc[3][i]);
    }
  }
#pragma unroll
  for (int j = 0; j < 4; ++j) {
    const int o = o0 + j;
    const int head = o >> 5, dd = o & 31;
#pragma unroll
    for (int i = 0; i < 8; ++i) {
      const int p = p0 + pl0 + i;
      out[((size_t)((n * 8 + head) * P + p)) * 32 + dd] = acc[j][i];
    }
  }
}

// ---------------------------------------------------------------------------
// Local-window attention v2: FOUR threads per (n, head, query pixel).
// Lane-split s = tid&3 handles ky rows {lo_y + s + 4j}. Each split keeps its
// own online-softmax state; states merged at the end with a 2-stage
// shfl_xor butterfly. 8x8 query tile per block -> grid (64, 16), 4096 waves.
// att[(g*32+vd)*4096 + p]   (channel-major for the output projection)
// ---------------------------------------------------------------------------
__global__ __launch_bounds__(256, 3) void attn_kernel(
    const float* __restrict__ q_l, const float* __restrict__ k_l,
    const float* __restrict__ v_l, const float* __restrict__ pfx,
    const float* __restrict__ pfy, const float* __restrict__ ab,
    const float* __restrict__ gb, float* __restrict__ att) {
  const int g = blockIdx.y;    // n*8 + head
  const int head = g & 7;
  const int tid = threadIdx.x;
  const int s = tid & 3;       // ky-split index
  const int qi = tid >> 2;     // 0..63: query within the 8x8 tile
  const int ty = (blockIdx.x >> 3) * 8, tx = (blockIdx.x & 7) * 8;
  const int y = ty + (qi >> 3);
  const int x = tx + (qi & 7);
  const int p = y * 64 + x;

  // q + geom_bias (for positional dots) and q + appr_bias (for K dot)
  float qg[32], qa[32];
  {
    const float4* qp =
        reinterpret_cast<const float4*>(q_l + ((size_t)g * PQ + p) * 32);
#pragma unroll
    for (int t = 0; t < 8; ++t) {
      const float4 v4 = qp[t];
      qg[4 * t + 0] = v4.x;
      qg[4 * t + 1] = v4.y;
      qg[4 * t + 2] = v4.z;
      qg[4 * t + 3] = v4.w;
    }
#pragma unroll
    for (int dd = 0; dd < 32; ++dd) {
      const float qv = qg[dd];
      qa[dd] = qv + ab[head * 32 + dd];
      qg[dd] = qv + gb[head * 32 + dd];
    }
  }

  const int lo_y = (y >= 16) ? ((y - 16) >> 1) : 0;
  const int hi_y = min(((y + 17) >> 1) + 1, 32);
  const int lo_x = (x >= 16) ? ((x - 16) >> 1) : 0;
  const int hi_x = min(((x + 17) >> 1) + 1, 32);

  // ex table: cooperatively computed across the 4 split-lanes, then
  // all-gathered with width-4 shuffles (compile-time indices only).
  float ex[WIN];
  {
    const float* pfx_base = pfx + ((size_t)(head * 64 + x) * 32) * 32;
    float exo[5];
#pragma unroll
    for (int j = 0; j < 5; ++j) {
      const int kx = lo_x + 4 * j + s;
      float e = 0.f;
      if (kx < hi_x) { DOT32(e, qg, pfx_base + kx * 32); }
      exo[j] = e;
    }
#pragma unroll
    for (int kxi = 0; kxi < WIN; ++kxi) {
      ex[kxi] = __shfl(exo[kxi >> 2], kxi & 3, 4);
    }
  }

  float m = NF, l = 0.f;
  float acc[32];
#pragma unroll
  for (int vd = 0; vd < 32; ++vd) acc[vd] = 0.f;

  const float* kg = k_l + (size_t)g * PKV * 32;
  const float* vg = v_l + (size_t)g * PKV * 32;
  const float* pfy_base = pfy + ((size_t)(head * 64 + y) * 32) * 32;

#pragma unroll 1
  for (int j = 0; j < 5; ++j) {
    const int ky = lo_y + s + 4 * j;
    if (ky >= hi_y) break;
    float eyv;
    DOT32(eyv, qg, pfy_base + ky * 32);
    const float* krow = kg + (size_t)ky * 32 * 32;
    const float* vrow = vg + (size_t)ky * 32 * 32;
#pragma unroll
    for (int kxi = 0; kxi < WIN; ++kxi) {
      const int kx = lo_x + kxi;
      const bool okx = (kx < hi_x);
      const int kxc = okx ? kx : 31;
      float qk;
      DOT32(qk, qa, krow + kxc * 32);
      float e = okx ? (eyv + ex[kxi] + qk) : NF;
      if (e > m) {  // rare after warmup
        const float sc = __expf(m - e);
        l *= sc;
#pragma unroll
        for (int vd = 0; vd < 32; ++vd) acc[vd] *= sc;
        m = e;
      }
      const float pe = __expf(e - m);  // masked: exp(-inf)=0
      l += pe;
      const float4* vr = reinterpret_cast<const float4*>(vrow + kxc * 32);
#pragma unroll
      for (int t = 0; t < 8; ++t) {
        const float4 vv = vr[t];
        acc[4 * t + 0] = fmaf(pe, vv.x, acc[4 * t + 0]);
        acc[4 * t + 1] = fmaf(pe, vv.y, acc[4 * t + 1]);
        acc[4 * t + 2] = fmaf(pe, vv.z, acc[4 * t + 2]);
        acc[4 * t + 3] = fmaf(pe, vv.w, acc[4 * t + 3]);
      }
    }
  }

  // Merge the 4 per-lane online-softmax states (every lane's window is
  // non-empty: min window is 9x9, so each of the 4 ky-splits has >=2 rows
  // and m is finite). Two-stage butterfly over lanes {s^1, s^2}.
#pragma unroll
  for (int stage = 1; stage <= 2; stage <<= 1) {
    const float mo = __shfl_xor(m, stage);
    const float mn = fmaxf(m, mo);
    const float sc = __expf(m - mn);
    l *= sc;
    l += __shfl_xor(l, stage);
#pragma unroll
    for (int vd = 0; vd < 32; ++vd) {
      acc[vd] *= sc;
      acc[vd] += __shfl_xor(acc[vd], stage);
    }
    m = mn;
  }

  if (s == 0) {
    const float inv = 1.f / l;
    float* ob = att + (size_t)g * 32 * PQ + p;
#pragma unroll
    for (int vd = 0; vd < 32; ++vd) ob[(size_t)vd * PQ] = acc[vd] * inv;
  }
}

// ---------------------------------------------------------------------------
// Output projection + bias + gamma*(.) + residual. (unchanged from R1)
// ---------------------------------------------------------------------------
__global__ __launch_bounds__(256) void proj_out_kernel(
    const float* __restrict__ att, const float* __restrict__ Wt,
    const float* __restrict__ bias, const float* __restrict__ gamma,
    const float* __restrict__ x_in, float* __restrict__ out) {
  const int n = blockIdx.y;
  const int p0 = blockIdx.x * 32;
  const float* An = att + (size_t)n * (CC * PQ);
  __shared__ float xs[256][32];
  const int tid = threadIdx.x;
  {
    const int pl = tid & 31;
    const int c0 = tid >> 5;
#pragma unroll
    for (int i = 0; i < 32; ++i) {
      const int c = i * 8 + c0;
      xs[c][pl] = An[(size_t)c * PQ + p0 + pl];
    }
  }
  __syncthreads();
  const int og = tid & 63, pg = tid >> 6;
  const int o0 = og * 4, pl0 = pg * 8;
  float acc[4][8];
#pragma unroll
  for (int j = 0; j < 4; ++j)
#pragma unroll
    for (int i = 0; i < 8; ++i) acc[j][i] = 0.f;
#pragma unroll 4
  for (int c = 0; c < 256; ++c) {
    const float4 wvv = *reinterpret_cast<const float4*>(Wt + c * 256 + o0);
#pragma unroll
    for (int i = 0; i < 8; ++i) {
      const float xv = xs[c][pl0 + i];
      acc[0][i] = fmaf(wvv.x, xv, acc[0][i]);
      acc[1][i] = fmaf(wvv.y, xv, acc[1][i]);
      acc[2][i] = fmaf(wvv.z, xv, acc[2][i]);
      acc[3][i] = fmaf(wvv.w, xv, acc[3][i]);
    }
  }
  const float gm = gamma[0];
#pragma unroll
  for (int j = 0; j < 4; ++j) {
    const int o = o0 + j;
    const float bj = bias[o];
#pragma unroll
    for (int i = 0; i < 8; ++i) {
      const size_t idx =
          (size_t)n * (CC * PQ) + (size_t)o * PQ + (p0 + pl0 + i);
      out[idx] = fmaf(gm, acc[j][i] + bj, x_in[idx]);
    }
  }
}

// ---------------------------------------------------------------------------
extern "C" void kernel_launch(void* const* d_in, const int* in_sizes, int n_in,
                              void* d_out, int out_size, void* d_ws,
                              size_t ws_size, hipStream_t stream) {
  const float* x = (const float*)d_in[0];
  const float* q_w = (const float*)d_in[1];
  const float* k_w = (const float*)d_in[2];
  const float* v_w = (const float*)d_in[3];
  const float* fcx_w = (const float*)d_in[4];
  const float* fcy_w = (const float*)d_in[5];
  const float* ab = (const float*)d_in[6];
  const float* gb = (const float*)d_in[7];
  const float* proj_w = (const float*)d_in[8];
  const float* proj_b = (const float*)d_in[9];
  const float* gamma = (const float*)d_in[10];
  float* out = (float*)d_out;

  float* ws = (float*)d_ws;
  float* q_l = ws;               // 2*8*4096*32 = 2097152
  float* k_l = q_l + 2097152;    // 2*8*1024*32 =  524288
  float* v_l = k_l + 524288;     //                524288
  float* pfx = v_l + 524288;     // 8*64*32*32  =  524288
  float* pfy = pfx + 524288;     //                524288
  float* att = pfy + 524288;     // 2*256*4096  = 2097152
  float* qwt = att + 2097152;    // 65536
  float* kwt = qwt + 65536;
  float* vwt = kwt + 65536;
  float* pwt = vwt + 65536;      // total 6553600 floats = 26.2 MB

  transpose4_kernel<<<dim3(256, 4), 256, 0, stream>>>(
      q_w, k_w, v_w, proj_w, qwt, kwt, vwt, pwt);
  posfeat_kernel<<<dim3(64, 32, 2), 256, 0, stream>>>(fcx_w, fcy_w, pfx, pfy);
  proj_kernel<0><<<dim3(128, 2), 256, 0, stream>>>(x, qwt, nullptr, q_l,
                                                   nullptr);
  proj_kernel<1><<<dim3(32, 2, 2), 256, 0, stream>>>(x, kwt, vwt, k_l, v_l);
  attn_kernel<<<dim3(64, 16), 256, 0, stream>>>(q_l, k_l, v_l, pfx, pfy, ab,
                                                gb, att);
  proj_out_kernel<<<dim3(128, 2), 256, 0, stream>>>(att, pwt, proj_b, gamma, x,
                                                    out);
}

// Round 3
// 250.846 us; speedup vs baseline: 3.8022x; 3.8022x over previous
//
#include <hip/hip_runtime.h>
#include <hip/hip_bf16.h>
#include <math.h>

// Problem sizes (fixed by the reference)
#define NB   2
#define CC   256
#define HH   64
#define WW   64
#define NH   8
#define DD   32
#define PQ   4096   // 64*64 queries per image
#define PKV  1024   // 32*32 kv per image

#define NF (-INFINITY)

typedef __attribute__((ext_vector_type(8))) short short8;
typedef __attribute__((ext_vector_type(4))) float f32x4;

// res = dot(qarr[0..31], ptr[0..31]) with 4 partial sums (ILP)
#define DOT32(res, qarr, ptr)                                    \
  {                                                              \
    const float4* _r = reinterpret_cast<const float4*>(ptr);     \
    float _s0 = 0.f, _s1 = 0.f, _s2 = 0.f, _s3 = 0.f;            \
    _Pragma("unroll")                                            \
    for (int _t = 0; _t < 8; ++_t) {                             \
      const float4 _v = _r[_t];                                  \
      _s0 = fmaf(qarr[4 * _t + 0], _v.x, _s0);                   \
      _s1 = fmaf(qarr[4 * _t + 1], _v.y, _s1);                   \
      _s2 = fmaf(qarr[4 * _t + 2], _v.z, _s2);                   \
      _s3 = fmaf(qarr[4 * _t + 3], _v.w, _s3);                   \
    }                                                            \
    res = (_s0 + _s1) + (_s2 + _s3);                             \
  }

// ---------------------------------------------------------------------------
// Transpose the four 256x256 weight matrices: Wt[c][o] = W[o][c]
// ---------------------------------------------------------------------------
__global__ __launch_bounds__(256) void transpose4_kernel(
    const float* __restrict__ a, const float* __restrict__ b,
    const float* __restrict__ c, const float* __restrict__ d,
    float* __restrict__ ta, float* __restrict__ tb,
    float* __restrict__ tc, float* __restrict__ td) {
  const int which = blockIdx.y;
  const float* src = (which == 0) ? a : (which == 1) ? b : (which == 2) ? c : d;
  float* dst = (which == 0) ? ta : (which == 1) ? tb : (which == 2) ? tc : td;
  const int idx = blockIdx.x * 256 + threadIdx.x;   // 65536 total
  const int o = idx >> 8, ch = idx & 255;
  dst[ch * 256 + o] = src[idx];
}

// ---------------------------------------------------------------------------
// Positional features: pf[head][i][k][dd] (fp32)
// ---------------------------------------------------------------------------
__global__ __launch_bounds__(256) void posfeat_kernel(
    const float* __restrict__ fcx, const float* __restrict__ fcy,
    float* __restrict__ pfx, float* __restrict__ pfy) {
  const int i = blockIdx.x;
  const int k = blockIdx.y;
  const int which = blockIdx.z;
  const float* FC = which ? fcy : fcx;
  float* OUT = which ? pfy : pfx;
  __shared__ __align__(16) float feat[128];
  const int tid = threadIdx.x;
  if (tid < 64) {
    const float diff = (float)(i - 2 * k);
    const float dm = powf(1000.f, (float)tid * (1.f / 64.f));
    const float aa = diff / dm;
    feat[tid] = sinf(aa);
    feat[tid + 64] = cosf(aa);
  }
  __syncthreads();
  const float4* row4 = reinterpret_cast<const float4*>(FC + tid * 128);
  const float4* f4 = reinterpret_cast<const float4*>(feat);
  float s0 = 0.f, s1 = 0.f, s2 = 0.f, s3 = 0.f;
#pragma unroll
  for (int f = 0; f < 32; ++f) {
    const float4 fv = f4[f];
    const float4 rv = row4[f];
    s0 = fmaf(fv.x, rv.x, s0);
    s1 = fmaf(fv.y, rv.y, s1);
    s2 = fmaf(fv.z, rv.z, s2);
    s3 = fmaf(fv.w, rv.w, s3);
  }
  const float s = ((s0 + s1) + (s2 + s3)) * 0.70710678118654752440f;
  OUT[(((size_t)(tid >> 5) * 64 + i) * 32 + k) * 32 + (tid & 31)] = s;
}

// ---------------------------------------------------------------------------
// QKV projection. MODE 0: q (fp32 out, all 4096 px); MODE 1: k/v (BF16 out,
// 1024 strided kv px; blockIdx.z selects k vs v).
// ---------------------------------------------------------------------------
template <int MODE>
__global__ __launch_bounds__(256) void proj_kernel(
    const float* __restrict__ X, const float* __restrict__ WtA,
    const float* __restrict__ WtB, void* __restrict__ outA,
    void* __restrict__ outB) {
  constexpr int P = (MODE == 0) ? PQ : PKV;
  const int n = blockIdx.y;
  const float* Wt = WtA;
  void* out = outA;
  if (MODE == 1 && blockIdx.z == 1) { Wt = WtB; out = outB; }
  const int p0 = blockIdx.x * 32;
  const float* Xn = X + (size_t)n * (CC * PQ);
  __shared__ float xs[256][32];
  const int tid = threadIdx.x;
  {
    const int pl = tid & 31;
    const int c0 = tid >> 5;  // 0..7
    const int p = p0 + pl;
    const int gp = (MODE == 0) ? p : ((p >> 5) * 128 + (p & 31) * 2);
#pragma unroll
    for (int i = 0; i < 32; ++i) {
      const int c = i * 8 + c0;
      xs[c][pl] = Xn[(size_t)c * PQ + gp];
    }
  }
  __syncthreads();
  const int og = tid & 63;   // 64 output groups of 4
  const int pg = tid >> 6;   // 4 pixel groups of 8
  const int o0 = og * 4;
  const int pl0 = pg * 8;
  float acc[4][8];
#pragma unroll
  for (int j = 0; j < 4; ++j)
#pragma unroll
    for (int i = 0; i < 8; ++i) acc[j][i] = 0.f;
#pragma unroll 4
  for (int c = 0; c < 256; ++c) {
    const float4 wv = *reinterpret_cast<const float4*>(Wt + c * 256 + o0);
#pragma unroll
    for (int i = 0; i < 8; ++i) {
      const float xv = xs[c][pl0 + i];
      acc[0][i] = fmaf(wv.x, xv, acc[0][i]);
      acc[1][i] = fmaf(wv.y, xv, acc[1][i]);
      acc[2][i] = fmaf(wv.z, xv, acc[2][i]);
      acc[3][i] = fmaf(wv.w, xv, acc[3][i]);
    }
  }
#pragma unroll
  for (int j = 0; j < 4; ++j) {
    const int o = o0 + j;
    const int head = o >> 5, dd = o & 31;
#pragma unroll
    for (int i = 0; i < 8; ++i) {
      const int p = p0 + pl0 + i;
      const size_t idx = ((size_t)((n * 8 + head) * P + p)) * 32 + dd;
      if (MODE == 0)
        ((float*)out)[idx] = acc[j][i];
      else
        ((__hip_bfloat16*)out)[idx] = __float2bfloat16(acc[j][i]);
    }
  }
}

// ---------------------------------------------------------------------------
// MFMA local-window attention.
// Block = 4 waves; wave = one query row (y fixed, 16 x's). ky range is
// wave-uniform; kx union (<=25) handled as 2 MFMA N-tiles with -inf masking.
// QK: mfma_f32_16x16x32_bf16, A = Q+ab frag, B = K frag (global, coalesced).
// Softmax in C-layout (row q = 4*(l>>4)+r, col = l&15), row-reduce via
// shfl_xor over the 16 col-lanes. P -> bf16 via wave-private LDS tile,
// re-read as A-frag. PV: 2 MFMA, B = V u16-gather from global (L1 strips).
// ex/ey positional dot tables computed once per wave into wave-private LDS.
// att[(g*32+vd)*PQ + p]
// ---------------------------------------------------------------------------
__global__ __launch_bounds__(256) void attn_mfma_kernel(
    const float* __restrict__ q_l, const __hip_bfloat16* __restrict__ k_lb,
    const __hip_bfloat16* __restrict__ v_lb, const float* __restrict__ pfx,
    const float* __restrict__ pfy, const float* __restrict__ ab,
    const float* __restrict__ gb, float* __restrict__ att) {
  const int g = blockIdx.y;    // n*8 + head
  const int head = g & 7;
  const int bx = blockIdx.x & 3;   // x-tile of 16
  const int by = blockIdx.x >> 2;  // y-tile of 4 rows
  const int tx = bx * 16;
  const int wv = threadIdx.x >> 6;
  const int y = by * 4 + wv;
  const int l = threadIdx.x & 63;
  const int lc = l & 15;   // col lane
  const int lq = l >> 4;   // quarter

  __shared__ float exbuf[4][16][32];           // [wave][q][kx_rel]
  __shared__ float eybuf[4][16][20];           // [wave][q][ky_idx]
  __shared__ __hip_bfloat16 pbuf[4][16][40];   // [wave][q][kx_rel] (padded)

  const int KLO = max((tx - 16) >> 1, 0);
  const int KHI = min(tx / 2 + 17, 32);
  const int SW = KHI - KLO;
  const int lo_y = max((y - 16) >> 1, 0);
  const int hi_y = min(((y + 17) >> 1) + 1, 32);
  const int NKY = hi_y - lo_y;

  // ---------- upfront phase: positional dot tables (fp32) ----------
  // dot-query for this lane: q = lc  (x = tx + lc)
  const int xq = tx + lc;
  const int pq_ = y * 64 + xq;
  float qgd[32];
  {
    const float4* qrow =
        reinterpret_cast<const float4*>(q_l + ((size_t)g * PQ + pq_) * 32);
    const float4* gb4 = reinterpret_cast<const float4*>(gb + head * 32);
#pragma unroll
    for (int t = 0; t < 8; ++t) {
      const float4 v = qrow[t];
      const float4 b = gb4[t];
      qgd[4 * t + 0] = v.x + b.x;
      qgd[4 * t + 1] = v.y + b.y;
      qgd[4 * t + 2] = v.z + b.z;
      qgd[4 * t + 3] = v.w + b.w;
    }
  }
  // ex[q=lc][c] = (q+gb) . pfx[head][xq][KLO+c]
  {
    const float* pfxh = pfx + ((size_t)(head * 64 + xq) * 32) * 32;
#pragma unroll 1
    for (int rep = 0; rep < 7; ++rep) {
      const int c = 4 * rep + lq;
      if (c < SW) {
        float e;
        DOT32(e, qgd, pfxh + (KLO + c) * 32);
        exbuf[wv][lc][c] = e;
      }
    }
  }
  // ey[q=lc][t] = (q+gb) . pfy[head][y][lo_y+t]
  {
    const float* pfyh = pfy + ((size_t)(head * 64 + y) * 32) * 32;
#pragma unroll 1
    for (int rep = 0; rep < 5; ++rep) {
      const int t = 4 * rep + lq;
      if (t < NKY) {
        float e;
        DOT32(e, qgd, pfyh + (lo_y + t) * 32);
        eybuf[wv][lc][t] = e;
      }
    }
  }

  // ---------- A-frag: Qa[row=lc][d = 8*lq + j] (q + appr_bias, bf16) ----------
  short8 qa;
  {
    const float* qp = q_l + ((size_t)g * PQ + pq_) * 32 + 8 * lq;
    const float* abp = ab + head * 32 + 8 * lq;
#pragma unroll
    for (int j = 0; j < 8; ++j) {
      const __hip_bfloat16 hb = __float2bfloat16(qp[j] + abp[j]);
      qa[j] = __builtin_bit_cast(short, hb);
    }
  }

  // per-q-row mask bounds (q = 4*lq + r)
  int lox[4], hix[4];
#pragma unroll
  for (int r = 0; r < 4; ++r) {
    const int xr = tx + 4 * lq + r;
    lox[r] = max((xr - 16) >> 1, 0);
    hix[r] = min(((xr + 17) >> 1) + 1, 32);
  }
  const int kx0 = KLO + lc;        // this lane's kx col, N-tile 0
  const int kx1 = KLO + 16 + lc;   // N-tile 1

  f32x4 acc0 = {0.f, 0.f, 0.f, 0.f};
  f32x4 acc1 = {0.f, 0.f, 0.f, 0.f};
  float m_[4] = {NF, NF, NF, NF};
  float ls[4] = {0.f, 0.f, 0.f, 0.f};

  // wave must not start reading ex/ey before its own writes complete; LDS
  // dependencies within a wave are tracked by the compiler (lgkmcnt).

#pragma unroll 1
  for (int t = 0; t < NKY; ++t) {
    const int ky = lo_y + t;
    const __hip_bfloat16* kb = k_lb + ((size_t)g * PKV + ky * 32) * 32;
    const __hip_bfloat16* vb = v_lb + ((size_t)g * PKV + ky * 32) * 32;
    // K frags (B-operand): lane holds K[kx(col=lc)][d = 8*lq + j]
    const short8 k0 =
        *reinterpret_cast<const short8*>(kb + min(kx0, 31) * 32 + 8 * lq);
    const short8 k1 =
        *reinterpret_cast<const short8*>(kb + min(kx1, 31) * 32 + 8 * lq);
    // V frags (B-operand): lane holds V[kx = 8*lq + j (rel)][vd = lc (+16)]
    short8 v0, v1;
#pragma unroll
    for (int j = 0; j < 8; ++j) {
      const int kxa = min(KLO + 8 * lq + j, 31);
      v0[j] = *reinterpret_cast<const short*>(vb + kxa * 32 + lc);
      v1[j] = *reinterpret_cast<const short*>(vb + kxa * 32 + 16 + lc);
    }
    f32x4 zero = {0.f, 0.f, 0.f, 0.f};
    f32x4 s0 = __builtin_amdgcn_mfma_f32_16x16x32_bf16(qa, k0, zero, 0, 0, 0);
    f32x4 s1 = __builtin_amdgcn_mfma_f32_16x16x32_bf16(qa, k1, zero, 0, 0, 0);

    // e assembly + online softmax (C-layout: row q = 4*lq + r, col lc)
#pragma unroll
    for (int r = 0; r < 4; ++r) {
      const float ey = eybuf[wv][4 * lq + r][t];
      const float a0 = s0[r] + ey + exbuf[wv][4 * lq + r][lc];
      const float a1 = s1[r] + ey + exbuf[wv][4 * lq + r][16 + lc];
      const float e0 = (kx0 >= lox[r] && kx0 < hix[r]) ? a0 : NF;
      const float e1 = (kx1 >= lox[r] && kx1 < hix[r]) ? a1 : NF;
      float mx = fmaxf(e0, e1);
#pragma unroll
      for (int st = 1; st <= 8; st <<= 1) mx = fmaxf(mx, __shfl_xor(mx, st));
      const float mn = fmaxf(m_[r], mx);
      const float sc = __expf(m_[r] - mn);
      m_[r] = mn;
      ls[r] *= sc;
      acc0[r] *= sc;
      acc1[r] *= sc;
      const float p0 = __expf(e0 - mn);
      const float p1 = __expf(e1 - mn);
      ls[r] += p0 + p1;
      pbuf[wv][4 * lq + r][lc] = __float2bfloat16(p0);
      pbuf[wv][4 * lq + r][16 + lc] = __float2bfloat16(p1);
    }
    // P as A-frag: lane reads P[row=lc][kx-chunk 8*lq .. +7]
    const short8 pf =
        *reinterpret_cast<const short8*>(&pbuf[wv][lc][8 * lq]);
    acc0 = __builtin_amdgcn_mfma_f32_16x16x32_bf16(pf, v0, acc0, 0, 0, 0);
    acc1 = __builtin_amdgcn_mfma_f32_16x16x32_bf16(pf, v1, acc1, 0, 0, 0);
  }

  // finalize: row-sum of ls over 16 col-lanes, normalize, scatter-store
#pragma unroll
  for (int r = 0; r < 4; ++r) {
    float L = ls[r];
#pragma unroll
    for (int st = 1; st <= 8; st <<= 1) L += __shfl_xor(L, st);
    const float inv = 1.f / L;
    const int p = y * 64 + tx + 4 * lq + r;
    att[((size_t)g * 32 + lc) * PQ + p] = acc0[r] * inv;
    att[((size_t)g * 32 + 16 + lc) * PQ + p] = acc1[r] * inv;
  }
}

// ---------------------------------------------------------------------------
// Output projection + bias + gamma*(.) + residual.
// ---------------------------------------------------------------------------
__global__ __launch_bounds__(256) void proj_out_kernel(
    const float* __restrict__ att, const float* __restrict__ Wt,
    const float* __restrict__ bias, const float* __restrict__ gamma,
    const float* __restrict__ x_in, float* __restrict__ out) {
  const int n = blockIdx.y;
  const int p0 = blockIdx.x * 32;
  const float* An = att + (size_t)n * (CC * PQ);
  __shared__ float xs[256][32];
  const int tid = threadIdx.x;
  {
    const int pl = tid & 31;
    const int c0 = tid >> 5;
#pragma unroll
    for (int i = 0; i < 32; ++i) {
      const int c = i * 8 + c0;
      xs[c][pl] = An[(size_t)c * PQ + p0 + pl];
    }
  }
  __syncthreads();
  const int og = tid & 63, pg = tid >> 6;
  const int o0 = og * 4, pl0 = pg * 8;
  float acc[4][8];
#pragma unroll
  for (int j = 0; j < 4; ++j)
#pragma unroll
    for (int i = 0; i < 8; ++i) acc[j][i] = 0.f;
#pragma unroll 4
  for (int c = 0; c < 256; ++c) {
    const float4 wvv = *reinterpret_cast<const float4*>(Wt + c * 256 + o0);
#pragma unroll
    for (int i = 0; i < 8; ++i) {
      const float xv = xs[c][pl0 + i];
      acc[0][i] = fmaf(wvv.x, xv, acc[0][i]);
      acc[1][i] = fmaf(wvv.y, xv, acc[1][i]);
      acc[2][i] = fmaf(wvv.z, xv, acc[2][i]);
      acc[3][i] = fmaf(wvv.w, xv, acc[3][i]);
    }
  }
  const float gm = gamma[0];
#pragma unroll
  for (int j = 0; j < 4; ++j) {
    const int o = o0 + j;
    const float bj = bias[o];
#pragma unroll
    for (int i = 0; i < 8; ++i) {
      const size_t idx =
          (size_t)n * (CC * PQ) + (size_t)o * PQ + (p0 + pl0 + i);
      out[idx] = fmaf(gm, acc[j][i] + bj, x_in[idx]);
    }
  }
}

// ---------------------------------------------------------------------------
extern "C" void kernel_launch(void* const* d_in, const int* in_sizes, int n_in,
                              void* d_out, int out_size, void* d_ws,
                              size_t ws_size, hipStream_t stream) {
  const float* x = (const float*)d_in[0];
  const float* q_w = (const float*)d_in[1];
  const float* k_w = (const float*)d_in[2];
  const float* v_w = (const float*)d_in[3];
  const float* fcx_w = (const float*)d_in[4];
  const float* fcy_w = (const float*)d_in[5];
  const float* ab = (const float*)d_in[6];
  const float* gb = (const float*)d_in[7];
  const float* proj_w = (const float*)d_in[8];
  const float* proj_b = (const float*)d_in[9];
  const float* gamma = (const float*)d_in[10];
  float* out = (float*)d_out;

  float* ws = (float*)d_ws;
  float* q_l = ws;               // 2*8*4096*32 fp32        = 2097152 f
  float* pfx = q_l + 2097152;    // 8*64*32*32 fp32         =  524288 f
  float* pfy = pfx + 524288;     //                            524288 f
  float* att = pfy + 524288;     // 2*256*4096 fp32         = 2097152 f
  float* qwt = att + 2097152;    // 65536 f
  float* kwt = qwt + 65536;
  float* vwt = kwt + 65536;
  float* pwt = vwt + 65536;
  __hip_bfloat16* k_lb = (__hip_bfloat16*)(pwt + 65536);  // 524288 bf16
  __hip_bfloat16* v_lb = k_lb + 524288;                   // 524288 bf16
  // total: 6029312 float-slots = 24.1 MB

  transpose4_kernel<<<dim3(256, 4), 256, 0, stream>>>(
      q_w, k_w, v_w, proj_w, qwt, kwt, vwt, pwt);
  posfeat_kernel<<<dim3(64, 32, 2), 256, 0, stream>>>(fcx_w, fcy_w, pfx, pfy);
  proj_kernel<0><<<dim3(128, 2), 256, 0, stream>>>(x, qwt, nullptr,
                                                   (void*)q_l, nullptr);
  proj_kernel<1><<<dim3(32, 2, 2), 256, 0, stream>>>(x, kwt, vwt, (void*)k_lb,
                                                     (void*)v_lb);
  attn_mfma_kernel<<<dim3(64, 16), 256, 0, stream>>>(q_l, k_lb, v_lb, pfx,
                                                     pfy, ab, gb, att);
  proj_out_kernel<<<dim3(128, 2), 256, 0, stream>>>(att, pwt, proj_b, gamma, x,
                                                    out);
}

// Round 4
// 184.444 us; speedup vs baseline: 5.1711x; 1.3600x over previous
//
#include <hip/hip_runtime.h>
#include <hip/hip_bf16.h>
#include <math.h>

// Problem sizes (fixed by the reference)
#define NB   2
#define CC   256
#define HH   64
#define WW   64
#define NH   8
#define DD   32
#define PQ   4096   // 64*64 queries per image
#define PKV  1024   // 32*32 kv per image
#define NDIFF 126   // distinct values of (i - 2k): [-62, 63]

#define NF (-INFINITY)

typedef __attribute__((ext_vector_type(8))) short short8;
typedef __attribute__((ext_vector_type(4))) float f32x4;

// res = dot(qarr[0..31], ptr[0..31]) with 4 partial sums (ILP)
#define DOT32(res, qarr, ptr)                                    \
  {                                                              \
    const float4* _r = reinterpret_cast<const float4*>(ptr);     \
    float _s0 = 0.f, _s1 = 0.f, _s2 = 0.f, _s3 = 0.f;            \
    _Pragma("unroll")                                            \
    for (int _t = 0; _t < 8; ++_t) {                             \
      const float4 _v = _r[_t];                                  \
      _s0 = fmaf(qarr[4 * _t + 0], _v.x, _s0);                   \
      _s1 = fmaf(qarr[4 * _t + 1], _v.y, _s1);                   \
      _s2 = fmaf(qarr[4 * _t + 2], _v.z, _s2);                   \
      _s3 = fmaf(qarr[4 * _t + 3], _v.w, _s3);                   \
    }                                                            \
    res = (_s0 + _s1) + (_s2 + _s3);                             \
  }

// ---------------------------------------------------------------------------
// Transpose the four 256x256 weight matrices: Wt[c][o] = W[o][c]
// ---------------------------------------------------------------------------
__global__ __launch_bounds__(256) void transpose4_kernel(
    const float* __restrict__ a, const float* __restrict__ b,
    const float* __restrict__ c, const float* __restrict__ d,
    float* __restrict__ ta, float* __restrict__ tb,
    float* __restrict__ tc, float* __restrict__ td) {
  const int which = blockIdx.y;
  const float* src = (which == 0) ? a : (which == 1) ? b : (which == 2) ? c : d;
  float* dst = (which == 0) ? ta : (which == 1) ? tb : (which == 2) ? tc : td;
  const int idx = blockIdx.x * 256 + threadIdx.x;   // 65536 total
  const int o = idx >> 8, ch = idx & 255;
  dst[ch * 256 + o] = src[idx];
}

// ---------------------------------------------------------------------------
// Positional feature tables, deduplicated over diff d = i - 2k:
//   pemb{x,y}[d+62][o] = (1/sqrt(2)) * sum_f feat(d)[f] * FC[o][f]
// feat = [sin(d/1000^(f/64)) f<64 | cos(...) f>=64].  126 x 256 each.
// grid (126, 2), 256 threads (one per output channel o).
// ---------------------------------------------------------------------------
__global__ __launch_bounds__(256) void posfeat_kernel(
    const float* __restrict__ fcx, const float* __restrict__ fcy,
    float* __restrict__ pembx, float* __restrict__ pemby) {
  const int dd = blockIdx.x;          // 0..125 -> diff = dd - 62
  const int which = blockIdx.y;
  const float* FC = which ? fcy : fcx;
  float* OUT = which ? pemby : pembx;
  __shared__ __align__(16) float feat[128];
  const int tid = threadIdx.x;
  if (tid < 64) {
    const float diff = (float)(dd - 62);
    const float dm = powf(1000.f, (float)tid * (1.f / 64.f));
    const float aa = diff / dm;
    feat[tid] = sinf(aa);
    feat[tid + 64] = cosf(aa);
  }
  __syncthreads();
  const float4* row4 = reinterpret_cast<const float4*>(FC + tid * 128);
  const float4* f4 = reinterpret_cast<const float4*>(feat);
  float s0 = 0.f, s1 = 0.f, s2 = 0.f, s3 = 0.f;
#pragma unroll
  for (int f = 0; f < 32; ++f) {
    const float4 fv = f4[f];
    const float4 rv = row4[f];
    s0 = fmaf(fv.x, rv.x, s0);
    s1 = fmaf(fv.y, rv.y, s1);
    s2 = fmaf(fv.z, rv.z, s2);
    s3 = fmaf(fv.w, rv.w, s3);
  }
  const float s = ((s0 + s1) + (s2 + s3)) * 0.70710678118654752440f;
  OUT[(size_t)dd * 256 + tid] = s;
}

// ---------------------------------------------------------------------------
// QKV projection. MODE 0: q (fp32 out, all 4096 px); MODE 1: k/v (BF16 out,
// 1024 strided kv px; blockIdx.z selects k vs v).
// ---------------------------------------------------------------------------
template <int MODE>
__global__ __launch_bounds__(256) void proj_kernel(
    const float* __restrict__ X, const float* __restrict__ WtA,
    const float* __restrict__ WtB, void* __restrict__ outA,
    void* __restrict__ outB) {
  constexpr int P = (MODE == 0) ? PQ : PKV;
  const int n = blockIdx.y;
  const float* Wt = WtA;
  void* out = outA;
  if (MODE == 1 && blockIdx.z == 1) { Wt = WtB; out = outB; }
  const int p0 = blockIdx.x * 32;
  const float* Xn = X + (size_t)n * (CC * PQ);
  __shared__ float xs[256][32];
  const int tid = threadIdx.x;
  {
    const int pl = tid & 31;
    const int c0 = tid >> 5;  // 0..7
    const int p = p0 + pl;
    const int gp = (MODE == 0) ? p : ((p >> 5) * 128 + (p & 31) * 2);
#pragma unroll
    for (int i = 0; i < 32; ++i) {
      const int c = i * 8 + c0;
      xs[c][pl] = Xn[(size_t)c * PQ + gp];
    }
  }
  __syncthreads();
  const int og = tid & 63;   // 64 output groups of 4
  const int pg = tid >> 6;   // 4 pixel groups of 8
  const int o0 = og * 4;
  const int pl0 = pg * 8;
  float acc[4][8];
#pragma unroll
  for (int j = 0; j < 4; ++j)
#pragma unroll
    for (int i = 0; i < 8; ++i) acc[j][i] = 0.f;
#pragma unroll 4
  for (int c = 0; c < 256; ++c) {
    const float4 wv = *reinterpret_cast<const float4*>(Wt + c * 256 + o0);
#pragma unroll
    for (int i = 0; i < 8; ++i) {
      const float xv = xs[c][pl0 + i];
      acc[0][i] = fmaf(wv.x, xv, acc[0][i]);
      acc[1][i] = fmaf(wv.y, xv, acc[1][i]);
      acc[2][i] = fmaf(wv.z, xv, acc[2][i]);
      acc[3][i] = fmaf(wv.w, xv, acc[3][i]);
    }
  }
#pragma unroll
  for (int j = 0; j < 4; ++j) {
    const int o = o0 + j;
    const int head = o >> 5, dd = o & 31;
#pragma unroll
    for (int i = 0; i < 8; ++i) {
      const int p = p0 + pl0 + i;
      const size_t idx = ((size_t)((n * 8 + head) * P + p)) * 32 + dd;
      if (MODE == 0)
        ((float*)out)[idx] = acc[j][i];
      else
        ((__hip_bfloat16*)out)[idx] = __float2bfloat16(acc[j][i]);
    }
  }
}

// ---------------------------------------------------------------------------
// MFMA local-window attention (same structure as R3; positional dots now
// read the deduplicated pembx/pemby[diff+62][256] tables, L1/L2-resident).
// ---------------------------------------------------------------------------
__global__ __launch_bounds__(256) void attn_mfma_kernel(
    const float* __restrict__ q_l, const __hip_bfloat16* __restrict__ k_lb,
    const __hip_bfloat16* __restrict__ v_lb, const float* __restrict__ pembx,
    const float* __restrict__ pemby, const float* __restrict__ ab,
    const float* __restrict__ gb, float* __restrict__ att) {
  const int g = blockIdx.y;    // n*8 + head
  const int head = g & 7;
  const int bx = blockIdx.x & 3;   // x-tile of 16
  const int by = blockIdx.x >> 2;  // y-tile of 4 rows
  const int tx = bx * 16;
  const int wv = threadIdx.x >> 6;
  const int y = by * 4 + wv;
  const int l = threadIdx.x & 63;
  const int lc = l & 15;   // col lane
  const int lq = l >> 4;   // quarter

  __shared__ float exbuf[4][16][32];           // [wave][q][kx_rel]
  __shared__ float eybuf[4][16][20];           // [wave][q][ky_idx]
  __shared__ __hip_bfloat16 pbuf[4][16][40];   // [wave][q][kx_rel] (padded)

  const int KLO = max((tx - 16) >> 1, 0);
  const int KHI = min(tx / 2 + 17, 32);
  const int SW = KHI - KLO;
  const int lo_y = max((y - 16) >> 1, 0);
  const int hi_y = min(((y + 17) >> 1) + 1, 32);
  const int NKY = hi_y - lo_y;

  // ---------- upfront phase: positional dot tables (fp32) ----------
  // dot-query for this lane: q = lc  (x = tx + lc)
  const int xq = tx + lc;
  const int pq_ = y * 64 + xq;
  float qgd[32];
  {
    const float4* qrow =
        reinterpret_cast<const float4*>(q_l + ((size_t)g * PQ + pq_) * 32);
    const float4* gb4 = reinterpret_cast<const float4*>(gb + head * 32);
#pragma unroll
    for (int t = 0; t < 8; ++t) {
      const float4 v = qrow[t];
      const float4 b = gb4[t];
      qgd[4 * t + 0] = v.x + b.x;
      qgd[4 * t + 1] = v.y + b.y;
      qgd[4 * t + 2] = v.z + b.z;
      qgd[4 * t + 3] = v.w + b.w;
    }
  }
  // ex[q=lc][c] = (q+gb) . pembx[xq - 2*(KLO+c) + 62]
  {
#pragma unroll 1
    for (int rep = 0; rep < 7; ++rep) {
      const int c = 4 * rep + lq;
      if (c < SW) {
        float e;
        DOT32(e, qgd,
              pembx + (size_t)(xq - 2 * (KLO + c) + 62) * 256 + head * 32);
        exbuf[wv][lc][c] = e;
      }
    }
  }
  // ey[q=lc][t] = (q+gb) . pemby[y - 2*(lo_y+t) + 62]
  {
#pragma unroll 1
    for (int rep = 0; rep < 5; ++rep) {
      const int t = 4 * rep + lq;
      if (t < NKY) {
        float e;
        DOT32(e, qgd,
              pemby + (size_t)(y - 2 * (lo_y + t) + 62) * 256 + head * 32);
        eybuf[wv][lc][t] = e;
      }
    }
  }

  // ---------- A-frag: Qa[row=lc][d = 8*lq + j] (q + appr_bias, bf16) ----------
  short8 qa;
  {
    const float* qp = q_l + ((size_t)g * PQ + pq_) * 32 + 8 * lq;
    const float* abp = ab + head * 32 + 8 * lq;
#pragma unroll
    for (int j = 0; j < 8; ++j) {
      const __hip_bfloat16 hb = __float2bfloat16(qp[j] + abp[j]);
      qa[j] = __builtin_bit_cast(short, hb);
    }
  }

  // per-q-row mask bounds (q = 4*lq + r)
  int lox[4], hix[4];
#pragma unroll
  for (int r = 0; r < 4; ++r) {
    const int xr = tx + 4 * lq + r;
    lox[r] = max((xr - 16) >> 1, 0);
    hix[r] = min(((xr + 17) >> 1) + 1, 32);
  }
  const int kx0 = KLO + lc;        // this lane's kx col, N-tile 0
  const int kx1 = KLO + 16 + lc;   // N-tile 1

  f32x4 acc0 = {0.f, 0.f, 0.f, 0.f};
  f32x4 acc1 = {0.f, 0.f, 0.f, 0.f};
  float m_[4] = {NF, NF, NF, NF};
  float ls[4] = {0.f, 0.f, 0.f, 0.f};

#pragma unroll 1
  for (int t = 0; t < NKY; ++t) {
    const int ky = lo_y + t;
    const __hip_bfloat16* kb = k_lb + ((size_t)g * PKV + ky * 32) * 32;
    const __hip_bfloat16* vb = v_lb + ((size_t)g * PKV + ky * 32) * 32;
    // K frags (B-operand): lane holds K[kx(col=lc)][d = 8*lq + j]
    const short8 k0 =
        *reinterpret_cast<const short8*>(kb + min(kx0, 31) * 32 + 8 * lq);
    const short8 k1 =
        *reinterpret_cast<const short8*>(kb + min(kx1, 31) * 32 + 8 * lq);
    // V frags (B-operand): lane holds V[kx = 8*lq + j (rel)][vd = lc (+16)]
    short8 v0, v1;
#pragma unroll
    for (int j = 0; j < 8; ++j) {
      const int kxa = min(KLO + 8 * lq + j, 31);
      v0[j] = *reinterpret_cast<const short*>(vb + kxa * 32 + lc);
      v1[j] = *reinterpret_cast<const short*>(vb + kxa * 32 + 16 + lc);
    }
    f32x4 zero = {0.f, 0.f, 0.f, 0.f};
    f32x4 s0 = __builtin_amdgcn_mfma_f32_16x16x32_bf16(qa, k0, zero, 0, 0, 0);
    f32x4 s1 = __builtin_amdgcn_mfma_f32_16x16x32_bf16(qa, k1, zero, 0, 0, 0);

    // e assembly + online softmax (C-layout: row q = 4*lq + r, col lc)
#pragma unroll
    for (int r = 0; r < 4; ++r) {
      const float ey = eybuf[wv][4 * lq + r][t];
      const float a0 = s0[r] + ey + exbuf[wv][4 * lq + r][lc];
      const float a1 = s1[r] + ey + exbuf[wv][4 * lq + r][16 + lc];
      const float e0 = (kx0 >= lox[r] && kx0 < hix[r]) ? a0 : NF;
      const float e1 = (kx1 >= lox[r] && kx1 < hix[r]) ? a1 : NF;
      float mx = fmaxf(e0, e1);
#pragma unroll
      for (int st = 1; st <= 8; st <<= 1) mx = fmaxf(mx, __shfl_xor(mx, st));
      const float mn = fmaxf(m_[r], mx);
      const float sc = __expf(m_[r] - mn);
      m_[r] = mn;
      ls[r] *= sc;
      acc0[r] *= sc;
      acc1[r] *= sc;
      const float p0 = __expf(e0 - mn);
      const float p1 = __expf(e1 - mn);
      ls[r] += p0 + p1;
      pbuf[wv][4 * lq + r][lc] = __float2bfloat16(p0);
      pbuf[wv][4 * lq + r][16 + lc] = __float2bfloat16(p1);
    }
    // P as A-frag: lane reads P[row=lc][kx-chunk 8*lq .. +7]
    const short8 pf =
        *reinterpret_cast<const short8*>(&pbuf[wv][lc][8 * lq]);
    acc0 = __builtin_amdgcn_mfma_f32_16x16x32_bf16(pf, v0, acc0, 0, 0, 0);
    acc1 = __builtin_amdgcn_mfma_f32_16x16x32_bf16(pf, v1, acc1, 0, 0, 0);
  }

  // finalize: row-sum of ls over 16 col-lanes, normalize, scatter-store
#pragma unroll
  for (int r = 0; r < 4; ++r) {
    float L = ls[r];
#pragma unroll
    for (int st = 1; st <= 8; st <<= 1) L += __shfl_xor(L, st);
    const float inv = 1.f / L;
    const int p = y * 64 + tx + 4 * lq + r;
    att[((size_t)g * 32 + lc) * PQ + p] = acc0[r] * inv;
    att[((size_t)g * 32 + 16 + lc) * PQ + p] = acc1[r] * inv;
  }
}

// ---------------------------------------------------------------------------
// Output projection + bias + gamma*(.) + residual.
// ---------------------------------------------------------------------------
__global__ __launch_bounds__(256) void proj_out_kernel(
    const float* __restrict__ att, const float* __restrict__ Wt,
    const float* __restrict__ bias, const float* __restrict__ gamma,
    const float* __restrict__ x_in, float* __restrict__ out) {
  const int n = blockIdx.y;
  const int p0 = blockIdx.x * 32;
  const float* An = att + (size_t)n * (CC * PQ);
  __shared__ float xs[256][32];
  const int tid = threadIdx.x;
  {
    const int pl = tid & 31;
    const int c0 = tid >> 5;
#pragma unroll
    for (int i = 0; i < 32; ++i) {
      const int c = i * 8 + c0;
      xs[c][pl] = An[(size_t)c * PQ + p0 + pl];
    }
  }
  __syncthreads();
  const int og = tid & 63, pg = tid >> 6;
  const int o0 = og * 4, pl0 = pg * 8;
  float acc[4][8];
#pragma unroll
  for (int j = 0; j < 4; ++j)
#pragma unroll
    for (int i = 0; i < 8; ++i) acc[j][i] = 0.f;
#pragma unroll 4
  for (int c = 0; c < 256; ++c) {
    const float4 wvv = *reinterpret_cast<const float4*>(Wt + c * 256 + o0);
#pragma unroll
    for (int i = 0; i < 8; ++i) {
      const float xv = xs[c][pl0 + i];
      acc[0][i] = fmaf(wvv.x, xv, acc[0][i]);
      acc[1][i] = fmaf(wvv.y, xv, acc[1][i]);
      acc[2][i] = fmaf(wvv.z, xv, acc[2][i]);
      acc[3][i] = fmaf(wvv.w, xv, acc[3][i]);
    }
  }
  const float gm = gamma[0];
#pragma unroll
  for (int j = 0; j < 4; ++j) {
    const int o = o0 + j;
    const float bj = bias[o];
#pragma unroll
    for (int i = 0; i < 8; ++i) {
      const size_t idx =
          (size_t)n * (CC * PQ) + (size_t)o * PQ + (p0 + pl0 + i);
      out[idx] = fmaf(gm, acc[j][i] + bj, x_in[idx]);
    }
  }
}

// ---------------------------------------------------------------------------
extern "C" void kernel_launch(void* const* d_in, const int* in_sizes, int n_in,
                              void* d_out, int out_size, void* d_ws,
                              size_t ws_size, hipStream_t stream) {
  const float* x = (const float*)d_in[0];
  const float* q_w = (const float*)d_in[1];
  const float* k_w = (const float*)d_in[2];
  const float* v_w = (const float*)d_in[3];
  const float* fcx_w = (const float*)d_in[4];
  const float* fcy_w = (const float*)d_in[5];
  const float* ab = (const float*)d_in[6];
  const float* gb = (const float*)d_in[7];
  const float* proj_w = (const float*)d_in[8];
  const float* proj_b = (const float*)d_in[9];
  const float* gamma = (const float*)d_in[10];
  float* out = (float*)d_out;

  float* ws = (float*)d_ws;
  float* q_l = ws;               // 2*8*4096*32 fp32        = 2097152 f
  float* att = q_l + 2097152;    // 2*256*4096 fp32         = 2097152 f
  float* qwt = att + 2097152;    // 65536 f
  float* kwt = qwt + 65536;
  float* vwt = kwt + 65536;
  float* pwt = vwt + 65536;
  float* pembx = pwt + 65536;    // 126*256 = 32256 f
  float* pemby = pembx + 32256;  // 32256 f
  __hip_bfloat16* k_lb = (__hip_bfloat16*)(pemby + 32256);  // 524288 bf16
  __hip_bfloat16* v_lb = k_lb + 524288;                     // 524288 bf16
  // total: ~5.07M float-slots = 20.3 MB

  transpose4_kernel<<<dim3(256, 4), 256, 0, stream>>>(
      q_w, k_w, v_w, proj_w, qwt, kwt, vwt, pwt);
  posfeat_kernel<<<dim3(126, 2), 256, 0, stream>>>(fcx_w, fcy_w, pembx, pemby);
  proj_kernel<0><<<dim3(128, 2), 256, 0, stream>>>(x, qwt, nullptr,
                                                   (void*)q_l, nullptr);
  proj_kernel<1><<<dim3(32, 2, 2), 256, 0, stream>>>(x, kwt, vwt, (void*)k_lb,
                                                     (void*)v_lb);
  attn_mfma_kernel<<<dim3(64, 16), 256, 0, stream>>>(q_l, k_lb, v_lb, pembx,
                                                     pemby, ab, gb, att);
  proj_out_kernel<<<dim3(128, 2), 256, 0, stream>>>(att, pwt, proj_b, gamma, x,
                                                    out);
}

// Round 5
// 179.420 us; speedup vs baseline: 5.3159x; 1.0280x over previous
//
#include <hip/hip_runtime.h>
#include <hip/hip_bf16.h>
#include <math.h>

// Problem sizes (fixed by the reference)
#define NB   2
#define CC   256
#define HH   64
#define WW   64
#define NH   8
#define DD   32
#define PQ   4096   // 64*64 queries per image
#define PKV  1024   // 32*32 kv per image
#define NDIFF 126   // distinct values of (i - 2k): [-62, 63]

#define NF (-INFINITY)
#define M0 24.0f    // fixed softmax offset (replaces online max; |e| << 80)

typedef __attribute__((ext_vector_type(8))) short short8;
typedef __attribute__((ext_vector_type(4))) float f32x4;

// res = dot(qarr[0..31], ptr[0..31]) with 4 partial sums (ILP)
#define DOT32(res, qarr, ptr)                                    \
  {                                                              \
    const float4* _r = reinterpret_cast<const float4*>(ptr);     \
    float _s0 = 0.f, _s1 = 0.f, _s2 = 0.f, _s3 = 0.f;            \
    _Pragma("unroll")                                            \
    for (int _t = 0; _t < 8; ++_t) {                             \
      const float4 _v = _r[_t];                                  \
      _s0 = fmaf(qarr[4 * _t + 0], _v.x, _s0);                   \
      _s1 = fmaf(qarr[4 * _t + 1], _v.y, _s1);                   \
      _s2 = fmaf(qarr[4 * _t + 2], _v.z, _s2);                   \
      _s3 = fmaf(qarr[4 * _t + 3], _v.w, _s3);                   \
    }                                                            \
    res = (_s0 + _s1) + (_s2 + _s3);                             \
  }

// ---------------------------------------------------------------------------
// Transpose the four 256x256 weight matrices: Wt[c][o] = W[o][c]
// ---------------------------------------------------------------------------
__global__ __launch_bounds__(256) void transpose4_kernel(
    const float* __restrict__ a, const float* __restrict__ b,
    const float* __restrict__ c, const float* __restrict__ d,
    float* __restrict__ ta, float* __restrict__ tb,
    float* __restrict__ tc, float* __restrict__ td) {
  const int which = blockIdx.y;
  const float* src = (which == 0) ? a : (which == 1) ? b : (which == 2) ? c : d;
  float* dst = (which == 0) ? ta : (which == 1) ? tb : (which == 2) ? tc : td;
  const int idx = blockIdx.x * 256 + threadIdx.x;   // 65536 total
  const int o = idx >> 8, ch = idx & 255;
  dst[ch * 256 + o] = src[idx];
}

// ---------------------------------------------------------------------------
// Positional feature tables, deduplicated over diff d = i - 2k:
//   pemb{x,y}[d+62][o] = (1/sqrt(2)) * sum_f feat(d)[f] * FC[o][f]
// ---------------------------------------------------------------------------
__global__ __launch_bounds__(256) void posfeat_kernel(
    const float* __restrict__ fcx, const float* __restrict__ fcy,
    float* __restrict__ pembx, float* __restrict__ pemby) {
  const int dd = blockIdx.x;          // 0..125 -> diff = dd - 62
  const int which = blockIdx.y;
  const float* FC = which ? fcy : fcx;
  float* OUT = which ? pemby : pembx;
  __shared__ __align__(16) float feat[128];
  const int tid = threadIdx.x;
  if (tid < 64) {
    const float diff = (float)(dd - 62);
    const float dm = powf(1000.f, (float)tid * (1.f / 64.f));
    const float aa = diff / dm;
    feat[tid] = sinf(aa);
    feat[tid + 64] = cosf(aa);
  }
  __syncthreads();
  const float4* row4 = reinterpret_cast<const float4*>(FC + tid * 128);
  const float4* f4 = reinterpret_cast<const float4*>(feat);
  float s0 = 0.f, s1 = 0.f, s2 = 0.f, s3 = 0.f;
#pragma unroll
  for (int f = 0; f < 32; ++f) {
    const float4 fv = f4[f];
    const float4 rv = row4[f];
    s0 = fmaf(fv.x, rv.x, s0);
    s1 = fmaf(fv.y, rv.y, s1);
    s2 = fmaf(fv.z, rv.z, s2);
    s3 = fmaf(fv.w, rv.w, s3);
  }
  const float s = ((s0 + s1) + (s2 + s3)) * 0.70710678118654752440f;
  OUT[(size_t)dd * 256 + tid] = s;
}

// ---------------------------------------------------------------------------
// QKV projection. MODE 0: q (fp32 out, all 4096 px); MODE 1: k/v (BF16 out,
// 1024 strided kv px). K layout: [g][p][dd] row-major. V layout: TRANSPOSED
// [g*32+vd][p] so the attention PV B-fragment is a contiguous b128 load.
// ---------------------------------------------------------------------------
template <int MODE>
__global__ __launch_bounds__(256) void proj_kernel(
    const float* __restrict__ X, const float* __restrict__ WtA,
    const float* __restrict__ WtB, void* __restrict__ outA,
    void* __restrict__ outB) {
  constexpr int P = (MODE == 0) ? PQ : PKV;
  const int n = blockIdx.y;
  const float* Wt = WtA;
  void* out = outA;
  bool isV = false;
  if (MODE == 1 && blockIdx.z == 1) { Wt = WtB; out = outB; isV = true; }
  const int p0 = blockIdx.x * 32;
  const float* Xn = X + (size_t)n * (CC * PQ);
  __shared__ float xs[256][32];
  const int tid = threadIdx.x;
  {
    const int pl = tid & 31;
    const int c0 = tid >> 5;  // 0..7
    const int p = p0 + pl;
    const int gp = (MODE == 0) ? p : ((p >> 5) * 128 + (p & 31) * 2);
#pragma unroll
    for (int i = 0; i < 32; ++i) {
      const int c = i * 8 + c0;
      xs[c][pl] = Xn[(size_t)c * PQ + gp];
    }
  }
  __syncthreads();
  const int og = tid & 63;   // 64 output groups of 4
  const int pg = tid >> 6;   // 4 pixel groups of 8
  const int o0 = og * 4;
  const int pl0 = pg * 8;
  float acc[4][8];
#pragma unroll
  for (int j = 0; j < 4; ++j)
#pragma unroll
    for (int i = 0; i < 8; ++i) acc[j][i] = 0.f;
#pragma unroll 4
  for (int c = 0; c < 256; ++c) {
    const float4 wv = *reinterpret_cast<const float4*>(Wt + c * 256 + o0);
#pragma unroll
    for (int i = 0; i < 8; ++i) {
      const float xv = xs[c][pl0 + i];
      acc[0][i] = fmaf(wv.x, xv, acc[0][i]);
      acc[1][i] = fmaf(wv.y, xv, acc[1][i]);
      acc[2][i] = fmaf(wv.z, xv, acc[2][i]);
      acc[3][i] = fmaf(wv.w, xv, acc[3][i]);
    }
  }
#pragma unroll
  for (int j = 0; j < 4; ++j) {
    const int o = o0 + j;
    const int head = o >> 5, dd = o & 31;
#pragma unroll
    for (int i = 0; i < 8; ++i) {
      const int p = p0 + pl0 + i;
      if (MODE == 0) {
        ((float*)out)[((size_t)((n * 8 + head) * P + p)) * 32 + dd] =
            acc[j][i];
      } else if (!isV) {
        ((__hip_bfloat16*)out)[((size_t)((n * 8 + head) * P + p)) * 32 + dd] =
            __float2bfloat16(acc[j][i]);
      } else {
        ((__hip_bfloat16*)out)[((size_t)((n * 8 + head)) * 32 + dd) * PKV + p] =
            __float2bfloat16(acc[j][i]);
      }
    }
  }
}

// ---------------------------------------------------------------------------
// MFMA local-window attention v2.
// Swapped QK: S^T = mfma(A=K, B=Qa) -> lane holds P[kx=4lq+r][q=lc].
// No-max softmax: p = exp(e - 24) in fp32 (energies bounded, no overflow);
// positional x-term AND window mask pre-baked into 8 per-lane registers
// (masked -> -inf). P->bf16 A-frag via cvt_pk + lane shuffles (no LDS).
// V read transposed (v_t[g*32+vd][p]) -> B-frag is one b128 load.
// ---------------------------------------------------------------------------
__global__ __launch_bounds__(256) void attn_mfma_kernel(
    const float* __restrict__ q_l, const __hip_bfloat16* __restrict__ k_lb,
    const __hip_bfloat16* __restrict__ v_t, const float* __restrict__ pembx,
    const float* __restrict__ pemby, const float* __restrict__ ab,
    const float* __restrict__ gb, float* __restrict__ att) {
  const int g = blockIdx.y;    // n*8 + head
  const int head = g & 7;
  const int bx = blockIdx.x & 3;   // x-tile of 16
  const int by = blockIdx.x >> 2;  // y-tile of 4 rows
  const int tx = bx * 16;
  const int wv = threadIdx.x >> 6;
  const int y = by * 4 + wv;
  const int l = threadIdx.x & 63;
  const int lc = l & 15;   // col lane (q for S^T / vd for O)
  const int lq = l >> 4;   // quarter

  __shared__ float exbuf[4][16][33];  // [wave][q][kx_rel]  (e or -inf)
  __shared__ float eybuf[4][16][21];  // [wave][q][ky_idx]  (ey - M0)

  const int KLO = max((tx - 16) >> 1, 0);
  const int lo_y = max((y - 16) >> 1, 0);
  const int hi_y = min(((y + 17) >> 1) + 1, 32);
  const int NKY = hi_y - lo_y;

  // ---------- upfront: positional dot tables (fp32), this lane = q=lc ----------
  const int xq = tx + lc;
  const int pq_ = y * 64 + xq;
  float qgd[32];
  {
    const float4* qrow =
        reinterpret_cast<const float4*>(q_l + ((size_t)g * PQ + pq_) * 32);
    const float4* gb4 = reinterpret_cast<const float4*>(gb + head * 32);
#pragma unroll
    for (int t = 0; t < 8; ++t) {
      const float4 v = qrow[t];
      const float4 b = gb4[t];
      qgd[4 * t + 0] = v.x + b.x;
      qgd[4 * t + 1] = v.y + b.y;
      qgd[4 * t + 2] = v.z + b.z;
      qgd[4 * t + 3] = v.w + b.w;
    }
  }
  {
    const int lox = max((xq - 16) >> 1, 0);
    const int hix = min(((xq + 17) >> 1) + 1, 32);
#pragma unroll 1
    for (int rep = 0; rep < 8; ++rep) {
      const int c = 4 * rep + lq;       // 0..31
      const int kx = KLO + c;
      float e = NF;
      if (kx >= lox && kx < hix) {
        DOT32(e, qgd, pembx + (size_t)(xq - 2 * kx + 62) * 256 + head * 32);
      }
      exbuf[wv][lc][c] = e;
    }
#pragma unroll 1
    for (int rep = 0; rep < 5; ++rep) {
      const int t = 4 * rep + lq;
      if (t < NKY) {
        float e;
        DOT32(e, qgd,
              pemby + (size_t)(y - 2 * (lo_y + t) + 62) * 256 + head * 32);
        eybuf[wv][lc][t] = e - M0;
      }
    }
  }

  // ---------- B-frag: Qa[d = 8*lq + j][q=lc] (q + appr_bias, bf16) ----------
  short8 qa;
  {
    const float* qp = q_l + ((size_t)g * PQ + pq_) * 32 + 8 * lq;
    const float* abp = ab + head * 32 + 8 * lq;
#pragma unroll
    for (int j = 0; j < 8; ++j) {
      const __hip_bfloat16 hb = __float2bfloat16(qp[j] + abp[j]);
      qa[j] = __builtin_bit_cast(short, hb);
    }
  }

  // per-lane loop-invariant ex registers (mask & x-positional term baked)
  float exC0[4], exC1[4];
#pragma unroll
  for (int r = 0; r < 4; ++r) {
    exC0[r] = exbuf[wv][lc][4 * lq + r];
    exC1[r] = exbuf[wv][lc][16 + 4 * lq + r];
  }
  const float* eyrow = &eybuf[wv][lc][0];

  // global bases (advance by t in the loop)
  const __hip_bfloat16* kb =
      k_lb + ((size_t)g * PKV + (size_t)lo_y * 32) * 32;
  const __hip_bfloat16* kb0 = kb + (KLO + lc) * 32 + 8 * lq;
  const __hip_bfloat16* kb1 = kb + min(KLO + 16 + lc, 31) * 32 + 8 * lq;
  const __hip_bfloat16* vb0 =
      v_t + ((size_t)g * 32 + lc) * PKV + (size_t)lo_y * 32 + KLO + 8 * lq;
  const __hip_bfloat16* vb1 = vb0 + 16 * PKV;

  f32x4 acc0 = {0.f, 0.f, 0.f, 0.f};
  f32x4 acc1 = {0.f, 0.f, 0.f, 0.f};
  float lp = 0.f;
  const int srcA = lc + ((l & 16) << 1);  // lane lc + 32*(lq&1)
  const int srcB = srcA + 16;
  const bool hiL = (l & 32) != 0;

#pragma unroll 1
  for (int t = 0; t < NKY; ++t) {
    const short8 k0 = *reinterpret_cast<const short8*>(kb0 + t * 1024);
    const short8 k1 = *reinterpret_cast<const short8*>(kb1 + t * 1024);
    const short8 v0 = *reinterpret_cast<const short8*>(vb0 + t * 32);
    const short8 v1 = *reinterpret_cast<const short8*>(vb1 + t * 32);
    const f32x4 zero = {0.f, 0.f, 0.f, 0.f};
    // S^T tiles: rows kx_local = 4*lq + r, cols q = lc
    const f32x4 s0 = __builtin_amdgcn_mfma_f32_16x16x32_bf16(k0, qa, zero, 0, 0, 0);
    const f32x4 s1 = __builtin_amdgcn_mfma_f32_16x16x32_bf16(k1, qa, zero, 0, 0, 0);
    const float eyC = eyrow[t];
    float p0[4], p1[4];
#pragma unroll
    for (int r = 0; r < 4; ++r) {
      p0[r] = __expf(s0[r] + exC0[r] + eyC);   // masked: exC=-inf -> 0
      p1[r] = __expf(s1[r] + exC1[r] + eyC);
    }
    lp += ((p0[0] + p0[1]) + (p0[2] + p0[3])) +
          ((p1[0] + p1[1]) + (p1[2] + p1[3]));
    // pack to bf16 pairs: w00=(k 4lq,4lq+1) w01=(k 4lq+2,+3) tile0; w1x tile1
    int w00, w01, w10, w11;
    asm("v_cvt_pk_bf16_f32 %0, %1, %2" : "=v"(w00) : "v"(p0[0]), "v"(p0[1]));
    asm("v_cvt_pk_bf16_f32 %0, %1, %2" : "=v"(w01) : "v"(p0[2]), "v"(p0[3]));
    asm("v_cvt_pk_bf16_f32 %0, %1, %2" : "=v"(w10) : "v"(p1[0]), "v"(p1[1]));
    asm("v_cvt_pk_bf16_f32 %0, %1, %2" : "=v"(w11) : "v"(p1[2]), "v"(p1[3]));
    // re-layout to PV A-frag: lane needs P[q=lc][k = 8*lq + j]
    const int a0 = __shfl(w00, srcA, 64), b0 = __shfl(w10, srcA, 64);
    const int a1 = __shfl(w01, srcA, 64), b1 = __shfl(w11, srcA, 64);
    const int a2 = __shfl(w00, srcB, 64), b2 = __shfl(w10, srcB, 64);
    const int a3 = __shfl(w01, srcB, 64), b3 = __shfl(w11, srcB, 64);
    int4 pw;
    pw.x = hiL ? b0 : a0;
    pw.y = hiL ? b1 : a1;
    pw.z = hiL ? b2 : a2;
    pw.w = hiL ? b3 : a3;
    const short8 pf = __builtin_bit_cast(short8, pw);
    acc0 = __builtin_amdgcn_mfma_f32_16x16x32_bf16(pf, v0, acc0, 0, 0, 0);
    acc1 = __builtin_amdgcn_mfma_f32_16x16x32_bf16(pf, v1, acc1, 0, 0, 0);
  }

  // l: sum over the 4 lq groups -> every lane holds L[q=lc]
  lp += __shfl_xor(lp, 16);
  lp += __shfl_xor(lp, 32);
  const float invall = 1.f / lp;
#pragma unroll
  for (int r = 0; r < 4; ++r) {
    const float inv = __shfl(invall, 4 * lq + r, 16);  // L for q = 4lq+r
    const int p = y * 64 + tx + 4 * lq + r;
    att[((size_t)g * 32 + lc) * PQ + p] = acc0[r] * inv;
    att[((size_t)g * 32 + 16 + lc) * PQ + p] = acc1[r] * inv;
  }
}

// ---------------------------------------------------------------------------
// Output projection + bias + gamma*(.) + residual.
// ---------------------------------------------------------------------------
__global__ __launch_bounds__(256) void proj_out_kernel(
    const float* __restrict__ att, const float* __restrict__ Wt,
    const float* __restrict__ bias, const float* __restrict__ gamma,
    const float* __restrict__ x_in, float* __restrict__ out) {
  const int n = blockIdx.y;
  const int p0 = blockIdx.x * 32;
  const float* An = att + (size_t)n * (CC * PQ);
  __shared__ float xs[256][32];
  const int tid = threadIdx.x;
  {
    const int pl = tid & 31;
    const int c0 = tid >> 5;
#pragma unroll
    for (int i = 0; i < 32; ++i) {
      const int c = i * 8 + c0;
      xs[c][pl] = An[(size_t)c * PQ + p0 + pl];
    }
  }
  __syncthreads();
  const int og = tid & 63, pg = tid >> 6;
  const int o0 = og * 4, pl0 = pg * 8;
  float acc[4][8];
#pragma unroll
  for (int j = 0; j < 4; ++j)
#pragma unroll
    for (int i = 0; i < 8; ++i) acc[j][i] = 0.f;
#pragma unroll 4
  for (int c = 0; c < 256; ++c) {
    const float4 wvv = *reinterpret_cast<const float4*>(Wt + c * 256 + o0);
#pragma unroll
    for (int i = 0; i < 8; ++i) {
      const float xv = xs[c][pl0 + i];
      acc[0][i] = fmaf(wvv.x, xv, acc[0][i]);
      acc[1][i] = fmaf(wvv.y, xv, acc[1][i]);
      acc[2][i] = fmaf(wvv.z, xv, acc[2][i]);
      acc[3][i] = fmaf(wvv.w, xv, acc[3][i]);
    }
  }
  const float gm = gamma[0];
#pragma unroll
  for (int j = 0; j < 4; ++j) {
    const int o = o0 + j;
    const float bj = bias[o];
#pragma unroll
    for (int i = 0; i < 8; ++i) {
      const size_t idx =
          (size_t)n * (CC * PQ) + (size_t)o * PQ + (p0 + pl0 + i);
      out[idx] = fmaf(gm, acc[j][i] + bj, x_in[idx]);
    }
  }
}

// ---------------------------------------------------------------------------
extern "C" void kernel_launch(void* const* d_in, const int* in_sizes, int n_in,
                              void* d_out, int out_size, void* d_ws,
                              size_t ws_size, hipStream_t stream) {
  const float* x = (const float*)d_in[0];
  const float* q_w = (const float*)d_in[1];
  const float* k_w = (const float*)d_in[2];
  const float* v_w = (const float*)d_in[3];
  const float* fcx_w = (const float*)d_in[4];
  const float* fcy_w = (const float*)d_in[5];
  const float* ab = (const float*)d_in[6];
  const float* gb = (const float*)d_in[7];
  const float* proj_w = (const float*)d_in[8];
  const float* proj_b = (const float*)d_in[9];
  const float* gamma = (const float*)d_in[10];
  float* out = (float*)d_out;

  float* ws = (float*)d_ws;
  float* q_l = ws;               // 2*8*4096*32 fp32        = 2097152 f
  float* att = q_l + 2097152;    // 2*256*4096 fp32         = 2097152 f
  float* qwt = att + 2097152;    // 65536 f
  float* kwt = qwt + 65536;
  float* vwt = kwt + 65536;
  float* pwt = vwt + 65536;
  float* pembx = pwt + 65536;    // 126*256 = 32256 f
  float* pemby = pembx + 32256;  // 32256 f
  __hip_bfloat16* k_lb = (__hip_bfloat16*)(pemby + 32256);  // 524288 bf16
  __hip_bfloat16* v_t = k_lb + 524288;   // 524288 bf16 (+64 f pad after)
  // total: ~5.07M float-slots + pad = ~20.3 MB

  transpose4_kernel<<<dim3(256, 4), 256, 0, stream>>>(
      q_w, k_w, v_w, proj_w, qwt, kwt, vwt, pwt);
  posfeat_kernel<<<dim3(126, 2), 256, 0, stream>>>(fcx_w, fcy_w, pembx, pemby);
  proj_kernel<0><<<dim3(128, 2), 256, 0, stream>>>(x, qwt, nullptr,
                                                   (void*)q_l, nullptr);
  proj_kernel<1><<<dim3(32, 2, 2), 256, 0, stream>>>(x, kwt, vwt, (void*)k_lb,
                                                     (void*)v_t);
  attn_mfma_kernel<<<dim3(64, 16), 256, 0, stream>>>(q_l, k_lb, v_t, pembx,
                                                     pemby, ab, gb, att);
  proj_out_kernel<<<dim3(128, 2), 256, 0, stream>>>(att, pwt, proj_b, gamma, x,
                                                    out);
}

// Round 6
// 168.095 us; speedup vs baseline: 5.6740x; 1.0674x over previous
//
#include <hip/hip_runtime.h>
#include <hip/hip_bf16.h>
#include <math.h>

// Problem sizes (fixed by the reference)
#define NB   2
#define CC   256
#define HH   64
#define WW   64
#define NH   8
#define DD   32
#define PQ   4096   // 64*64 queries per image
#define PKV  1024   // 32*32 kv per image
#define NDIFF 126   // distinct values of (i - 2k): [-62, 63]

#define NF (-INFINITY)
#define M0 24.0f    // fixed softmax offset (baked into EX; |e| << 80)
#define EXSTRIDE 36
#define EYSTRIDE 20

typedef __attribute__((ext_vector_type(8))) short short8;
typedef __attribute__((ext_vector_type(4))) float f32x4;

// ---------------------------------------------------------------------------
// Transpose the four 256x256 weight matrices: Wt[c][o] = W[o][c]
// ---------------------------------------------------------------------------
__global__ __launch_bounds__(256) void transpose4_kernel(
    const float* __restrict__ a, const float* __restrict__ b,
    const float* __restrict__ c, const float* __restrict__ d,
    float* __restrict__ ta, float* __restrict__ tb,
    float* __restrict__ tc, float* __restrict__ td) {
  const int which = blockIdx.y;
  const float* src = (which == 0) ? a : (which == 1) ? b : (which == 2) ? c : d;
  float* dst = (which == 0) ? ta : (which == 1) ? tb : (which == 2) ? tc : td;
  const int idx = blockIdx.x * 256 + threadIdx.x;   // 65536 total
  const int o = idx >> 8, ch = idx & 255;
  dst[ch * 256 + o] = src[idx];
}

// ---------------------------------------------------------------------------
// Positional feature tables (bf16), deduplicated over diff d = i - 2k:
//   pemb{x,y}_b[d+62][o] = (1/sqrt(2)) * sum_f feat(d)[f] * FC[o][f]
// ---------------------------------------------------------------------------
__global__ __launch_bounds__(256) void posfeat_kernel(
    const float* __restrict__ fcx, const float* __restrict__ fcy,
    __hip_bfloat16* __restrict__ pembx_b, __hip_bfloat16* __restrict__ pemby_b) {
  const int dd = blockIdx.x;          // 0..125 -> diff = dd - 62
  const int which = blockIdx.y;
  const float* FC = which ? fcy : fcx;
  __hip_bfloat16* OUT = which ? pemby_b : pembx_b;
  __shared__ __align__(16) float feat[128];
  const int tid = threadIdx.x;
  if (tid < 64) {
    const float diff = (float)(dd - 62);
    const float dm = powf(1000.f, (float)tid * (1.f / 64.f));
    const float aa = diff / dm;
    feat[tid] = sinf(aa);
    feat[tid + 64] = cosf(aa);
  }
  __syncthreads();
  const float4* row4 = reinterpret_cast<const float4*>(FC + tid * 128);
  const float4* f4 = reinterpret_cast<const float4*>(feat);
  float s0 = 0.f, s1 = 0.f, s2 = 0.f, s3 = 0.f;
#pragma unroll
  for (int f = 0; f < 32; ++f) {
    const float4 fv = f4[f];
    const float4 rv = row4[f];
    s0 = fmaf(fv.x, rv.x, s0);
    s1 = fmaf(fv.y, rv.y, s1);
    s2 = fmaf(fv.z, rv.z, s2);
    s3 = fmaf(fv.w, rv.w, s3);
  }
  const float s = ((s0 + s1) + (s2 + s3)) * 0.70710678118654752440f;
  OUT[(size_t)dd * 256 + tid] = __float2bfloat16(s);
}

// ---------------------------------------------------------------------------
// QKV projection.
// MODE 0: q over 4096 px -> TWO bf16 outputs: qab = q+appr_bias, qgb = q+geom_bias.
// MODE 1: k/v over 1024 strided kv px (z selects). K: [g][p][dd]. V transposed
// [g*32+vd][p].
// ---------------------------------------------------------------------------
template <int MODE>
__global__ __launch_bounds__(256) void proj_kernel(
    const float* __restrict__ X, const float* __restrict__ WtA,
    const float* __restrict__ WtB, void* __restrict__ outA,
    void* __restrict__ outB, const float* __restrict__ bA,
    const float* __restrict__ bB) {
  constexpr int P = (MODE == 0) ? PQ : PKV;
  const int n = blockIdx.y;
  const float* Wt = WtA;
  void* out = outA;
  bool isV = false;
  if (MODE == 1 && blockIdx.z == 1) { Wt = WtB; out = outB; isV = true; }
  const int p0 = blockIdx.x * 32;
  const float* Xn = X + (size_t)n * (CC * PQ);
  __shared__ float xs[256][32];
  const int tid = threadIdx.x;
  {
    const int pl = tid & 31;
    const int c0 = tid >> 5;  // 0..7
    const int p = p0 + pl;
    const int gp = (MODE == 0) ? p : ((p >> 5) * 128 + (p & 31) * 2);
#pragma unroll
    for (int i = 0; i < 32; ++i) {
      const int c = i * 8 + c0;
      xs[c][pl] = Xn[(size_t)c * PQ + gp];
    }
  }
  __syncthreads();
  const int og = tid & 63;   // 64 output groups of 4
  const int pg = tid >> 6;   // 4 pixel groups of 8
  const int o0 = og * 4;
  const int pl0 = pg * 8;
  float acc[4][8];
#pragma unroll
  for (int j = 0; j < 4; ++j)
#pragma unroll
    for (int i = 0; i < 8; ++i) acc[j][i] = 0.f;
#pragma unroll 4
  for (int c = 0; c < 256; ++c) {
    const float4 wv = *reinterpret_cast<const float4*>(Wt + c * 256 + o0);
#pragma unroll
    for (int i = 0; i < 8; ++i) {
      const float xv = xs[c][pl0 + i];
      acc[0][i] = fmaf(wv.x, xv, acc[0][i]);
      acc[1][i] = fmaf(wv.y, xv, acc[1][i]);
      acc[2][i] = fmaf(wv.z, xv, acc[2][i]);
      acc[3][i] = fmaf(wv.w, xv, acc[3][i]);
    }
  }
#pragma unroll
  for (int j = 0; j < 4; ++j) {
    const int o = o0 + j;
    const int head = o >> 5, dd = o & 31;
#pragma unroll
    for (int i = 0; i < 8; ++i) {
      const int p = p0 + pl0 + i;
      const size_t idx = ((size_t)((n * 8 + head) * P + p)) * 32 + dd;
      if (MODE == 0) {
        ((__hip_bfloat16*)outA)[idx] = __float2bfloat16(acc[j][i] + bA[o]);
        ((__hip_bfloat16*)outB)[idx] = __float2bfloat16(acc[j][i] + bB[o]);
      } else if (!isV) {
        ((__hip_bfloat16*)out)[idx] = __float2bfloat16(acc[j][i]);
      } else {
        ((__hip_bfloat16*)out)[((size_t)((n * 8 + head)) * 32 + dd) * PKV + p] =
            __float2bfloat16(acc[j][i]);
      }
    }
  }
}

// ---------------------------------------------------------------------------
// Positional energy tables via MFMA.
// MODE 0 (EX): block (x, g). EX[g][p][kx] = (q_p+gb).pembx[x-2kx] - M0 for
//   kx in [lox(x),hix(x)), else -1e30. Stride 36; slots 32..35 = -1e30.
// MODE 1 (EY): block (y, g). EY[g][p][t] = (q_p+gb).pemby[y-2(lo_y+t)],
//   t in [0,20). Stride 20.
// Each wave: 16 rows (p's) x 32 cols via 2 mfma_16x16x32_bf16.
// ---------------------------------------------------------------------------
template <int MODE>
__global__ __launch_bounds__(256) void exy_kernel(
    const __hip_bfloat16* __restrict__ qgb_b,
    const __hip_bfloat16* __restrict__ pemb_b, float* __restrict__ OUT) {
  const int i = blockIdx.x;       // x (MODE0) or y (MODE1)
  const int g = blockIdx.y;
  const int head = g & 7;
  const int wv = threadIdx.x >> 6;
  const int l = threadIdx.x & 63;
  const int lc = l & 15, lq = l >> 4;

  // A-frag: A[row=lc][d=8lq+j], rows = 16 pixels of this wave
  const int rowi = wv * 16 + lc;  // y (MODE0) or x (MODE1)
  const int p = (MODE == 0) ? rowi * 64 + i : i * 64 + rowi;
  const short8 a = *reinterpret_cast<const short8*>(
      (const short*)qgb_b + ((size_t)g * PQ + p) * 32 + 8 * lq);

  // B-frags: B[d=8lq+j][col=lc]
  int drow0, drow1;
  if (MODE == 0) {
    drow0 = i - 2 * lc + 62;
    drow1 = i - 2 * (lc + 16) + 62;
  } else {
    const int lo_y = max((i - 16) >> 1, 0);
    drow0 = i - 2 * (lo_y + lc) + 62;
    drow1 = i - 2 * (lo_y + lc + 16) + 62;
  }
  const short8 b0 = *reinterpret_cast<const short8*>(
      (const short*)pemb_b + (size_t)drow0 * 256 + head * 32 + 8 * lq);
  const short8 b1 = *reinterpret_cast<const short8*>(
      (const short*)pemb_b + (size_t)drow1 * 256 + head * 32 + 8 * lq);

  const f32x4 zero = {0.f, 0.f, 0.f, 0.f};
  const f32x4 c0 = __builtin_amdgcn_mfma_f32_16x16x32_bf16(a, b0, zero, 0, 0, 0);
  const f32x4 c1 = __builtin_amdgcn_mfma_f32_16x16x32_bf16(a, b1, zero, 0, 0, 0);

  // C layout: col = lc, row = 4*lq + r  (row within the wave's 16 pixels)
#pragma unroll
  for (int r = 0; r < 4; ++r) {
    const int rowr = wv * 16 + 4 * lq + r;
    const int pr = (MODE == 0) ? rowr * 64 + i : i * 64 + rowr;
    if (MODE == 0) {
      const int lox = max((i - 16) >> 1, 0);
      const int hix = min(((i + 17) >> 1) + 1, 32);
      float* o = OUT + ((size_t)g * PQ + pr) * EXSTRIDE;
      o[lc] = (lc >= lox && lc < hix) ? (c0[r] - M0) : -1e30f;
      o[16 + lc] = (lc + 16 >= lox && lc + 16 < hix) ? (c1[r] - M0) : -1e30f;
      if (lc < 4) o[32 + lc] = -1e30f;
    } else {
      float* o = OUT + ((size_t)g * PQ + pr) * EYSTRIDE;
      o[lc] = c0[r];
      if (lc < 4) o[16 + lc] = c1[r];
    }
  }
}

// ---------------------------------------------------------------------------
// MFMA local-window attention v3 (lean prologue).
// Swapped QK: S^T = mfma(A=K, B=Qa) -> lane holds P[kx=4lq+r][q=lc].
// p = exp(s + EX[..] + EY[..]); EX carries the -M0 offset and the -inf mask.
// P->bf16 A-frag via cvt_pk + lane shuffles (no LDS). V read transposed.
// ---------------------------------------------------------------------------
__global__ __launch_bounds__(256) void attn_mfma_kernel(
    const __hip_bfloat16* __restrict__ qab_b,
    const __hip_bfloat16* __restrict__ k_lb,
    const __hip_bfloat16* __restrict__ v_t, const float* __restrict__ EX,
    const float* __restrict__ EY, float* __restrict__ att) {
  const int g = blockIdx.y;    // n*8 + head
  const int bx = blockIdx.x & 3;   // x-tile of 16
  const int by = blockIdx.x >> 2;  // y-tile of 4 rows
  const int tx = bx * 16;
  const int wv = threadIdx.x >> 6;
  const int y = by * 4 + wv;
  const int l = threadIdx.x & 63;
  const int lc = l & 15;   // col lane (q for S^T / vd for O)
  const int lq = l >> 4;   // quarter

  __shared__ float eybuf[4][EYSTRIDE][16];  // [wave][t][q] - conflict-free read

  const int KLO = max((tx - 16) >> 1, 0);
  const int lo_y = max((y - 16) >> 1, 0);
  const int hi_y = min(((y + 17) >> 1) + 1, 32);
  const int NKY = hi_y - lo_y;

  const int xq = tx + lc;
  const int pq_ = y * 64 + xq;

  // Qa B-frag: lane holds Qa[d=8lq+j][q=lc]  (one 16B gather)
  const short8 qa = *reinterpret_cast<const short8*>(
      (const short*)qab_b + ((size_t)g * PQ + pq_) * 32 + 8 * lq);

  // per-lane loop-invariant ex registers (mask, M0, x-positional term baked)
  const float* exr = EX + ((size_t)g * PQ + pq_) * EXSTRIDE;
  float exC0[4], exC1[4];
#pragma unroll
  for (int r = 0; r < 4; ++r) {
    exC0[r] = exr[KLO + 4 * lq + r];
    exC1[r] = exr[min(KLO + 16 + 4 * lq + r, 35)];
  }

  // ey -> LDS (per-wave private; [t][q] layout for conflict-free loop reads)
  {
    const float* eyr = EY + ((size_t)g * PQ + pq_) * EYSTRIDE;
    const float4 e4 = *reinterpret_cast<const float4*>(eyr + 4 * lq);
#pragma unroll
    for (int j = 0; j < 4; ++j) eybuf[wv][4 * lq + j][lc] = e4[j];
    if (lq == 0) {
      const float4 e4b = *reinterpret_cast<const float4*>(eyr + 16);
#pragma unroll
      for (int j = 0; j < 4; ++j) eybuf[wv][16 + j][lc] = e4b[j];
    }
  }

  // global bases (advance by t in the loop)
  const __hip_bfloat16* kb =
      k_lb + ((size_t)g * PKV + (size_t)lo_y * 32) * 32;
  const __hip_bfloat16* kb0 = kb + (KLO + lc) * 32 + 8 * lq;
  const __hip_bfloat16* kb1 = kb + min(KLO + 16 + lc, 31) * 32 + 8 * lq;
  const __hip_bfloat16* vb0 =
      v_t + ((size_t)g * 32 + lc) * PKV + (size_t)lo_y * 32 + KLO + 8 * lq;
  const __hip_bfloat16* vb1 = vb0 + 16 * PKV;

  f32x4 acc0 = {0.f, 0.f, 0.f, 0.f};
  f32x4 acc1 = {0.f, 0.f, 0.f, 0.f};
  float lp = 0.f;
  const int srcA = lc + ((l & 16) << 1);  // lane lc + 32*(lq&1)
  const int srcB = srcA + 16;
  const bool hiL = (l & 32) != 0;

#pragma unroll 1
  for (int t = 0; t < NKY; ++t) {
    const short8 k0 = *reinterpret_cast<const short8*>(kb0 + t * 1024);
    const short8 k1 = *reinterpret_cast<const short8*>(kb1 + t * 1024);
    const short8 v0 = *reinterpret_cast<const short8*>(vb0 + t * 32);
    const short8 v1 = *reinterpret_cast<const short8*>(vb1 + t * 32);
    const f32x4 zero = {0.f, 0.f, 0.f, 0.f};
    // S^T tiles: rows kx_local = 4*lq + r, cols q = lc
    const f32x4 s0 = __builtin_amdgcn_mfma_f32_16x16x32_bf16(k0, qa, zero, 0, 0, 0);
    const f32x4 s1 = __builtin_amdgcn_mfma_f32_16x16x32_bf16(k1, qa, zero, 0, 0, 0);
    const float eyC = eybuf[wv][t][lc];
    float p0[4], p1[4];
#pragma unroll
    for (int r = 0; r < 4; ++r) {
      p0[r] = __expf(s0[r] + exC0[r] + eyC);   // masked: exC=-1e30 -> 0
      p1[r] = __expf(s1[r] + exC1[r] + eyC);
    }
    lp += ((p0[0] + p0[1]) + (p0[2] + p0[3])) +
          ((p1[0] + p1[1]) + (p1[2] + p1[3]));
    // pack to bf16 pairs
    int w00, w01, w10, w11;
    asm("v_cvt_pk_bf16_f32 %0, %1, %2" : "=v"(w00) : "v"(p0[0]), "v"(p0[1]));
    asm("v_cvt_pk_bf16_f32 %0, %1, %2" : "=v"(w01) : "v"(p0[2]), "v"(p0[3]));
    asm("v_cvt_pk_bf16_f32 %0, %1, %2" : "=v"(w10) : "v"(p1[0]), "v"(p1[1]));
    asm("v_cvt_pk_bf16_f32 %0, %1, %2" : "=v"(w11) : "v"(p1[2]), "v"(p1[3]));
    // re-layout to PV A-frag: lane needs P[q=lc][k = 8*lq + j]
    const int a0 = __shfl(w00, srcA, 64), b0 = __shfl(w10, srcA, 64);
    const int a1 = __shfl(w01, srcA, 64), b1 = __shfl(w11, srcA, 64);
    const int a2 = __shfl(w00, srcB, 64), b2 = __shfl(w10, srcB, 64);
    const int a3 = __shfl(w01, srcB, 64), b3 = __shfl(w11, srcB, 64);
    int4 pw;
    pw.x = hiL ? b0 : a0;
    pw.y = hiL ? b1 : a1;
    pw.z = hiL ? b2 : a2;
    pw.w = hiL ? b3 : a3;
    const short8 pf = __builtin_bit_cast(short8, pw);
    acc0 = __builtin_amdgcn_mfma_f32_16x16x32_bf16(pf, v0, acc0, 0, 0, 0);
    acc1 = __builtin_amdgcn_mfma_f32_16x16x32_bf16(pf, v1, acc1, 0, 0, 0);
  }

  // l: sum over the 4 lq groups -> every lane holds L[q=lc]
  lp += __shfl_xor(lp, 16);
  lp += __shfl_xor(lp, 32);
  const float invall = 1.f / lp;
#pragma unroll
  for (int r = 0; r < 4; ++r) {
    const float inv = __shfl(invall, 4 * lq + r, 16);  // L for q = 4lq+r
    const int p = y * 64 + tx + 4 * lq + r;
    att[((size_t)g * 32 + lc) * PQ + p] = acc0[r] * inv;
    att[((size_t)g * 32 + 16 + lc) * PQ + p] = acc1[r] * inv;
  }
}

// ---------------------------------------------------------------------------
// Output projection + bias + gamma*(.) + residual.
// ---------------------------------------------------------------------------
__global__ __launch_bounds__(256) void proj_out_kernel(
    const float* __restrict__ att, const float* __restrict__ Wt,
    const float* __restrict__ bias, const float* __restrict__ gamma,
    const float* __restrict__ x_in, float* __restrict__ out) {
  const int n = blockIdx.y;
  const int p0 = blockIdx.x * 32;
  const float* An = att + (size_t)n * (CC * PQ);
  __shared__ float xs[256][32];
  const int tid = threadIdx.x;
  {
    const int pl = tid & 31;
    const int c0 = tid >> 5;
#pragma unroll
    for (int i = 0; i < 32; ++i) {
      const int c = i * 8 + c0;
      xs[c][pl] = An[(size_t)c * PQ + p0 + pl];
    }
  }
  __syncthreads();
  const int og = tid & 63, pg = tid >> 6;
  const int o0 = og * 4, pl0 = pg * 8;
  float acc[4][8];
#pragma unroll
  for (int j = 0; j < 4; ++j)
#pragma unroll
    for (int i = 0; i < 8; ++i) acc[j][i] = 0.f;
#pragma unroll 4
  for (int c = 0; c < 256; ++c) {
    const float4 wvv = *reinterpret_cast<const float4*>(Wt + c * 256 + o0);
#pragma unroll
    for (int i = 0; i < 8; ++i) {
      const float xv = xs[c][pl0 + i];
      acc[0][i] = fmaf(wvv.x, xv, acc[0][i]);
      acc[1][i] = fmaf(wvv.y, xv, acc[1][i]);
      acc[2][i] = fmaf(wvv.z, xv, acc[2][i]);
      acc[3][i] = fmaf(wvv.w, xv, acc[3][i]);
    }
  }
  const float gm = gamma[0];
#pragma unroll
  for (int j = 0; j < 4; ++j) {
    const int o = o0 + j;
    const float bj = bias[o];
#pragma unroll
    for (int i = 0; i < 8; ++i) {
      const size_t idx =
          (size_t)n * (CC * PQ) + (size_t)o * PQ + (p0 + pl0 + i);
      out[idx] = fmaf(gm, acc[j][i] + bj, x_in[idx]);
    }
  }
}

// ---------------------------------------------------------------------------
extern "C" void kernel_launch(void* const* d_in, const int* in_sizes, int n_in,
                              void* d_out, int out_size, void* d_ws,
                              size_t ws_size, hipStream_t stream) {
  const float* x = (const float*)d_in[0];
  const float* q_w = (const float*)d_in[1];
  const float* k_w = (const float*)d_in[2];
  const float* v_w = (const float*)d_in[3];
  const float* fcx_w = (const float*)d_in[4];
  const float* fcy_w = (const float*)d_in[5];
  const float* ab = (const float*)d_in[6];
  const float* gb = (const float*)d_in[7];
  const float* proj_w = (const float*)d_in[8];
  const float* proj_b = (const float*)d_in[9];
  const float* gamma = (const float*)d_in[10];
  float* out = (float*)d_out;

  float* ws = (float*)d_ws;
  float* att = ws;                       // 2*256*4096        = 2,097,152 f
  float* qwt = att + 2097152;            // 65,536 f
  float* kwt = qwt + 65536;
  float* vwt = kwt + 65536;
  float* pwt = vwt + 65536;
  float* EX = pwt + 65536;               // 16*4096*36 = 2,359,296 f
  float* EY = EX + 2359296;              // 16*4096*20 = 1,310,720 f
  __hip_bfloat16* pembx_b = (__hip_bfloat16*)(EY + 1310720);  // 32,256 bf16
  __hip_bfloat16* pemby_b = pembx_b + 32256;                  // 32,256 bf16
  __hip_bfloat16* qab_b = pemby_b + 32256;   // 2*8*4096*32 = 2,097,152 bf16
  __hip_bfloat16* qgb_b = qab_b + 2097152;   // 2,097,152 bf16
  __hip_bfloat16* k_lb = qgb_b + 2097152;    //   524,288 bf16
  __hip_bfloat16* v_t = k_lb + 524288;       //   524,288 bf16
  // total = 8,683,008 float-slots = 34.7 MB

  transpose4_kernel<<<dim3(256, 4), 256, 0, stream>>>(
      q_w, k_w, v_w, proj_w, qwt, kwt, vwt, pwt);
  posfeat_kernel<<<dim3(126, 2), 256, 0, stream>>>(fcx_w, fcy_w, pembx_b,
                                                   pemby_b);
  proj_kernel<0><<<dim3(128, 2), 256, 0, stream>>>(
      x, qwt, nullptr, (void*)qab_b, (void*)qgb_b, ab, gb);
  proj_kernel<1><<<dim3(32, 2, 2), 256, 0, stream>>>(
      x, kwt, vwt, (void*)k_lb, (void*)v_t, nullptr, nullptr);
  exy_kernel<0><<<dim3(64, 16), 256, 0, stream>>>(qgb_b, pembx_b, EX);
  exy_kernel<1><<<dim3(64, 16), 256, 0, stream>>>(qgb_b, pemby_b, EY);
  attn_mfma_kernel<<<dim3(64, 16), 256, 0, stream>>>(qab_b, k_lb, v_t, EX, EY,
                                                     att);
  proj_out_kernel<<<dim3(128, 2), 256, 0, stream>>>(att, pwt, proj_b, gamma, x,
                                                    out);
}

// Round 9
// 152.590 us; speedup vs baseline: 6.2505x; 1.1016x over previous
//
#include <hip/hip_runtime.h>
#include <hip/hip_bf16.h>
#include <math.h>

// Problem sizes (fixed by the reference)
#define NB   2
#define CC   256
#define PQ   4096   // 64*64 queries per image
#define PKV  1024   // 32*32 kv per image

#define NF (-INFINITY)
#define M0 24.0f    // fixed softmax offset (baked into EX; |e| << 80)
#define EXSTRIDE 36
#define EYSTRIDE 20

typedef __attribute__((ext_vector_type(8))) short short8;
typedef __attribute__((ext_vector_type(4))) float f32x4;

// ---------------------------------------------------------------------------
// Transpose the four 256x256 weight matrices: Wt[c][o] = W[o][c]  (fp32)
// ---------------------------------------------------------------------------
__global__ __launch_bounds__(256) void transpose4_kernel(
    const float* __restrict__ a, const float* __restrict__ b,
    const float* __restrict__ c, const float* __restrict__ d,
    float* __restrict__ ta, float* __restrict__ tb,
    float* __restrict__ tc, float* __restrict__ td) {
  const int which = blockIdx.y;
  const float* src = (which == 0) ? a : (which == 1) ? b : (which == 2) ? c : d;
  float* dst = (which == 0) ? ta : (which == 1) ? tb : (which == 2) ? tc : td;
  const int idx = blockIdx.x * 256 + threadIdx.x;   // 65536 total
  const int o = idx >> 8, ch = idx & 255;
  dst[ch * 256 + o] = src[idx];
}

// ---------------------------------------------------------------------------
// Positional feature tables (bf16), deduplicated over diff d = i - 2k
// ---------------------------------------------------------------------------
__global__ __launch_bounds__(256) void posfeat_kernel(
    const float* __restrict__ fcx, const float* __restrict__ fcy,
    __hip_bfloat16* __restrict__ pembx_b, __hip_bfloat16* __restrict__ pemby_b) {
  const int dd = blockIdx.x;          // 0..125 -> diff = dd - 62
  const int which = blockIdx.y;
  const float* FC = which ? fcy : fcx;
  __hip_bfloat16* OUT = which ? pemby_b : pembx_b;
  __shared__ __align__(16) float feat[128];
  const int tid = threadIdx.x;
  if (tid < 64) {
    const float diff = (float)(dd - 62);
    const float dm = powf(1000.f, (float)tid * (1.f / 64.f));
    const float aa = diff / dm;
    feat[tid] = sinf(aa);
    feat[tid + 64] = cosf(aa);
  }
  __syncthreads();
  const float4* row4 = reinterpret_cast<const float4*>(FC + tid * 128);
  const float4* f4 = reinterpret_cast<const float4*>(feat);
  float s0 = 0.f, s1 = 0.f, s2 = 0.f, s3 = 0.f;
#pragma unroll
  for (int f = 0; f < 32; ++f) {
    const float4 fv = f4[f];
    const float4 rv = row4[f];
    s0 = fmaf(fv.x, rv.x, s0);
    s1 = fmaf(fv.y, rv.y, s1);
    s2 = fmaf(fv.z, rv.z, s2);
    s3 = fmaf(fv.w, rv.w, s3);
  }
  const float s = ((s0 + s1) + (s2 + s3)) * 0.70710678118654752440f;
  OUT[(size_t)dd * 256 + tid] = __float2bfloat16(s);
}

// ---------------------------------------------------------------------------
// QKV projection (R6-proven math; grid split 4x along outputs for occupancy).
// MODE 0: q -> TWO bf16 outputs: qab = q+appr_bias, qgb = q+geom_bias.
//   grid (128 p-tiles, n, q4);  block: 64 outputs x 32 px; thread 4o x 2px.
// MODE 1: k/v over 1024 strided kv px; grid (32 p-tiles * 4 q4, n, isV).
//   K: [g][p][dd]. V transposed [g*32+dd][p].
// ---------------------------------------------------------------------------
template <int MODE>
__global__ __launch_bounds__(256) void proj_kernel(
    const float* __restrict__ X, const float* __restrict__ WtA,
    const float* __restrict__ WtB, void* __restrict__ outA,
    void* __restrict__ outB, const float* __restrict__ bA,
    const float* __restrict__ bB) {
  constexpr int P = (MODE == 0) ? PQ : PKV;
  const int n = blockIdx.y;
  const float* Wt = WtA;
  void* out = outA;
  bool isV = false;
  if (MODE == 1 && blockIdx.z == 1) { Wt = WtB; out = outB; isV = true; }
  int p0, q4;
  if (MODE == 0) {
    p0 = blockIdx.x * 32;
    q4 = blockIdx.z;
  } else {
    p0 = (blockIdx.x >> 2) * 32;
    q4 = blockIdx.x & 3;
  }
  const float* Xn = X + (size_t)n * (CC * PQ);
  __shared__ float xs[256][32];
  const int tid = threadIdx.x;
  {
    const int pl = tid & 31;
    const int c0 = tid >> 5;  // 0..7
    const int p = p0 + pl;
    const int gp = (MODE == 0) ? p : ((p >> 5) * 128 + (p & 31) * 2);
#pragma unroll
    for (int i = 0; i < 32; ++i) {
      const int c = i * 8 + c0;
      xs[c][pl] = Xn[(size_t)c * PQ + gp];
    }
  }
  __syncthreads();
  const int og = tid & 15;   // 16 output groups of 4 -> 64 outputs
  const int pg = tid >> 4;   // 16 pixel groups of 2  -> 32 px
  const int o0 = q4 * 64 + og * 4;
  const int pl0 = pg * 2;
  float acc[4][2];
#pragma unroll
  for (int j = 0; j < 4; ++j)
#pragma unroll
    for (int i = 0; i < 2; ++i) acc[j][i] = 0.f;
#pragma unroll 4
  for (int c = 0; c < 256; ++c) {
    const float4 wv = *reinterpret_cast<const float4*>(Wt + c * 256 + o0);
#pragma unroll
    for (int i = 0; i < 2; ++i) {
      const float xv = xs[c][pl0 + i];
      acc[0][i] = fmaf(wv.x, xv, acc[0][i]);
      acc[1][i] = fmaf(wv.y, xv, acc[1][i]);
      acc[2][i] = fmaf(wv.z, xv, acc[2][i]);
      acc[3][i] = fmaf(wv.w, xv, acc[3][i]);
    }
  }
#pragma unroll
  for (int j = 0; j < 4; ++j) {
    const int o = o0 + j;
    const int head = o >> 5, dd = o & 31;
#pragma unroll
    for (int i = 0; i < 2; ++i) {
      const int p = p0 + pl0 + i;
      const size_t idx = ((size_t)((n * 8 + head) * P + p)) * 32 + dd;
      if (MODE == 0) {
        ((__hip_bfloat16*)outA)[idx] = __float2bfloat16(acc[j][i] + bA[o]);
        ((__hip_bfloat16*)outB)[idx] = __float2bfloat16(acc[j][i] + bB[o]);
      } else if (!isV) {
        ((__hip_bfloat16*)out)[idx] = __float2bfloat16(acc[j][i]);
      } else {
        ((__hip_bfloat16*)out)[((size_t)((n * 8 + head)) * 32 + dd) * PKV + p] =
            __float2bfloat16(acc[j][i]);
      }
    }
  }
}

// ---------------------------------------------------------------------------
// Positional energy tables via MFMA (R6-proven, unchanged).
// ---------------------------------------------------------------------------
template <int MODE>
__global__ __launch_bounds__(256) void exy_kernel(
    const __hip_bfloat16* __restrict__ qgb_b,
    const __hip_bfloat16* __restrict__ pemb_b, float* __restrict__ OUT) {
  const int i = blockIdx.x;       // x (MODE0) or y (MODE1)
  const int g = blockIdx.y;
  const int head = g & 7;
  const int wv = threadIdx.x >> 6;
  const int l = threadIdx.x & 63;
  const int lc = l & 15, lq = l >> 4;

  const int rowi = wv * 16 + lc;  // y (MODE0) or x (MODE1)
  const int p = (MODE == 0) ? rowi * 64 + i : i * 64 + rowi;
  const short8 a = *reinterpret_cast<const short8*>(
      (const short*)qgb_b + ((size_t)g * PQ + p) * 32 + 8 * lq);

  int drow0, drow1;
  if (MODE == 0) {
    drow0 = i - 2 * lc + 62;
    drow1 = i - 2 * (lc + 16) + 62;
  } else {
    const int lo_y = max((i - 16) >> 1, 0);
    drow0 = i - 2 * (lo_y + lc) + 62;
    drow1 = i - 2 * (lo_y + lc + 16) + 62;
  }
  const short8 b0 = *reinterpret_cast<const short8*>(
      (const short*)pemb_b + (size_t)drow0 * 256 + head * 32 + 8 * lq);
  const short8 b1 = *reinterpret_cast<const short8*>(
      (const short*)pemb_b + (size_t)drow1 * 256 + head * 32 + 8 * lq);

  const f32x4 zero = {0.f, 0.f, 0.f, 0.f};
  const f32x4 c0 = __builtin_amdgcn_mfma_f32_16x16x32_bf16(a, b0, zero, 0, 0, 0);
  const f32x4 c1 = __builtin_amdgcn_mfma_f32_16x16x32_bf16(a, b1, zero, 0, 0, 0);

#pragma unroll
  for (int r = 0; r < 4; ++r) {
    const int rowr = wv * 16 + 4 * lq + r;
    const int pr = (MODE == 0) ? rowr * 64 + i : i * 64 + rowr;
    if (MODE == 0) {
      const int lox = max((i - 16) >> 1, 0);
      const int hix = min(((i + 17) >> 1) + 1, 32);
      float* o = OUT + ((size_t)g * PQ + pr) * EXSTRIDE;
      o[lc] = (lc >= lox && lc < hix) ? (c0[r] - M0) : -1e30f;
      o[16 + lc] = (lc + 16 >= lox && lc + 16 < hix) ? (c1[r] - M0) : -1e30f;
      if (lc < 4) o[32 + lc] = -1e30f;
    } else {
      float* o = OUT + ((size_t)g * PQ + pr) * EYSTRIDE;
      o[lc] = c0[r];
      if (lc < 4) o[16 + lc] = c1[r];
    }
  }
}

// ---------------------------------------------------------------------------
// MFMA local-window attention (R6-proven, unchanged; fp32 att store).
// ---------------------------------------------------------------------------
__global__ __launch_bounds__(256) void attn_mfma_kernel(
    const __hip_bfloat16* __restrict__ qab_b,
    const __hip_bfloat16* __restrict__ k_lb,
    const __hip_bfloat16* __restrict__ v_t, const float* __restrict__ EX,
    const float* __restrict__ EY, float* __restrict__ att) {
  const int g = blockIdx.y;    // n*8 + head
  const int bx = blockIdx.x & 3;   // x-tile of 16
  const int by = blockIdx.x >> 2;  // y-tile of 4 rows
  const int tx = bx * 16;
  const int wv = threadIdx.x >> 6;
  const int y = by * 4 + wv;
  const int l = threadIdx.x & 63;
  const int lc = l & 15;   // col lane (q for S^T / vd for O)
  const int lq = l >> 4;   // quarter

  __shared__ float eybuf[4][EYSTRIDE][16];  // [wave][t][q]

  const int KLO = max((tx - 16) >> 1, 0);
  const int lo_y = max((y - 16) >> 1, 0);
  const int hi_y = min(((y + 17) >> 1) + 1, 32);
  const int NKY = hi_y - lo_y;

  const int xq = tx + lc;
  const int pq_ = y * 64 + xq;

  // Qa B-frag: lane holds Qa[d=8lq+j][q=lc]
  const short8 qa = *reinterpret_cast<const short8*>(
      (const short*)qab_b + ((size_t)g * PQ + pq_) * 32 + 8 * lq);

  // per-lane loop-invariant ex registers (mask, M0, x-positional term baked)
  const float* exr = EX + ((size_t)g * PQ + pq_) * EXSTRIDE;
  float exC0[4], exC1[4];
#pragma unroll
  for (int r = 0; r < 4; ++r) {
    exC0[r] = exr[KLO + 4 * lq + r];
    exC1[r] = exr[min(KLO + 16 + 4 * lq + r, 35)];
  }

  // ey -> LDS ([t][q] layout for conflict-free loop reads)
  {
    const float* eyr = EY + ((size_t)g * PQ + pq_) * EYSTRIDE;
    const float4 e4 = *reinterpret_cast<const float4*>(eyr + 4 * lq);
#pragma unroll
    for (int j = 0; j < 4; ++j) eybuf[wv][4 * lq + j][lc] = e4[j];
    if (lq == 0) {
      const float4 e4b = *reinterpret_cast<const float4*>(eyr + 16);
#pragma unroll
      for (int j = 0; j < 4; ++j) eybuf[wv][16 + j][lc] = e4b[j];
    }
  }

  const __hip_bfloat16* kb =
      k_lb + ((size_t)g * PKV + (size_t)lo_y * 32) * 32;
  const __hip_bfloat16* kb0 = kb + (KLO + lc) * 32 + 8 * lq;
  const __hip_bfloat16* kb1 = kb + min(KLO + 16 + lc, 31) * 32 + 8 * lq;
  const __hip_bfloat16* vb0 =
      v_t + ((size_t)g * 32 + lc) * PKV + (size_t)lo_y * 32 + KLO + 8 * lq;
  const __hip_bfloat16* vb1 = vb0 + 16 * PKV;

  f32x4 acc0 = {0.f, 0.f, 0.f, 0.f};
  f32x4 acc1 = {0.f, 0.f, 0.f, 0.f};
  float lp = 0.f;
  const int srcA = lc + ((l & 16) << 1);  // lane lc + 32*(lq&1)
  const int srcB = srcA + 16;
  const bool hiL = (l & 32) != 0;

#pragma unroll 1
  for (int t = 0; t < NKY; ++t) {
    const short8 k0 = *reinterpret_cast<const short8*>(kb0 + t * 1024);
    const short8 k1 = *reinterpret_cast<const short8*>(kb1 + t * 1024);
    const short8 v0 = *reinterpret_cast<const short8*>(vb0 + t * 32);
    const short8 v1 = *reinterpret_cast<const short8*>(vb1 + t * 32);
    const f32x4 zero = {0.f, 0.f, 0.f, 0.f};
    // S^T tiles: rows kx_local = 4*lq + r, cols q = lc
    const f32x4 s0 = __builtin_amdgcn_mfma_f32_16x16x32_bf16(k0, qa, zero, 0, 0, 0);
    const f32x4 s1 = __builtin_amdgcn_mfma_f32_16x16x32_bf16(k1, qa, zero, 0, 0, 0);
    const float eyC = eybuf[wv][t][lc];
    float p0[4], p1[4];
#pragma unroll
    for (int r = 0; r < 4; ++r) {
      p0[r] = __expf(s0[r] + exC0[r] + eyC);   // masked: exC=-1e30 -> 0
      p1[r] = __expf(s1[r] + exC1[r] + eyC);
    }
    lp += ((p0[0] + p0[1]) + (p0[2] + p0[3])) +
          ((p1[0] + p1[1]) + (p1[2] + p1[3]));
    int w00, w01, w10, w11;
    asm("v_cvt_pk_bf16_f32 %0, %1, %2" : "=v"(w00) : "v"(p0[0]), "v"(p0[1]));
    asm("v_cvt_pk_bf16_f32 %0, %1, %2" : "=v"(w01) : "v"(p0[2]), "v"(p0[3]));
    asm("v_cvt_pk_bf16_f32 %0, %1, %2" : "=v"(w10) : "v"(p1[0]), "v"(p1[1]));
    asm("v_cvt_pk_bf16_f32 %0, %1, %2" : "=v"(w11) : "v"(p1[2]), "v"(p1[3]));
    const int a0 = __shfl(w00, srcA, 64), b0 = __shfl(w10, srcA, 64);
    const int a1 = __shfl(w01, srcA, 64), b1 = __shfl(w11, srcA, 64);
    const int a2 = __shfl(w00, srcB, 64), b2 = __shfl(w10, srcB, 64);
    const int a3 = __shfl(w01, srcB, 64), b3 = __shfl(w11, srcB, 64);
    int4 pw;
    pw.x = hiL ? b0 : a0;
    pw.y = hiL ? b1 : a1;
    pw.z = hiL ? b2 : a2;
    pw.w = hiL ? b3 : a3;
    const short8 pf = __builtin_bit_cast(short8, pw);
    acc0 = __builtin_amdgcn_mfma_f32_16x16x32_bf16(pf, v0, acc0, 0, 0, 0);
    acc1 = __builtin_amdgcn_mfma_f32_16x16x32_bf16(pf, v1, acc1, 0, 0, 0);
  }

  // l: sum over the 4 lq groups -> every lane holds L[q=lc]
  lp += __shfl_xor(lp, 16);
  lp += __shfl_xor(lp, 32);
  const float invall = 1.f / lp;
#pragma unroll
  for (int r = 0; r < 4; ++r) {
    const float inv = __shfl(invall, 4 * lq + r, 16);  // L for q = 4lq+r
    const int p = y * 64 + tx + 4 * lq + r;
    att[((size_t)g * 32 + lc) * PQ + p] = acc0[r] * inv;
    att[((size_t)g * 32 + 16 + lc) * PQ + p] = acc1[r] * inv;
  }
}

// ---------------------------------------------------------------------------
// Output projection + bias + gamma*(.) + residual (R6 math; grid split 4x
// along outputs: block = 64 outputs x 32 px; thread = 4o x 2px).
// ---------------------------------------------------------------------------
__global__ __launch_bounds__(256) void proj_out_kernel(
    const float* __restrict__ att, const float* __restrict__ Wt,
    const float* __restrict__ bias, const float* __restrict__ gamma,
    const float* __restrict__ x_in, float* __restrict__ out) {
  const int n = blockIdx.y;
  const int p0 = blockIdx.x * 32;
  const int q4 = blockIdx.z;
  const float* An = att + (size_t)n * (CC * PQ);
  __shared__ float xs[256][32];
  const int tid = threadIdx.x;
  {
    const int pl = tid & 31;
    const int c0 = tid >> 5;
#pragma unroll
    for (int i = 0; i < 32; ++i) {
      const int c = i * 8 + c0;
      xs[c][pl] = An[(size_t)c * PQ + p0 + pl];
    }
  }
  __syncthreads();
  const int og = tid & 15, pg = tid >> 4;
  const int o0 = q4 * 64 + og * 4, pl0 = pg * 2;
  float acc[4][2];
#pragma unroll
  for (int j = 0; j < 4; ++j)
#pragma unroll
    for (int i = 0; i < 2; ++i) acc[j][i] = 0.f;
#pragma unroll 4
  for (int c = 0; c < 256; ++c) {
    const float4 wvv = *reinterpret_cast<const float4*>(Wt + c * 256 + o0);
#pragma unroll
    for (int i = 0; i < 2; ++i) {
      const float xv = xs[c][pl0 + i];
      acc[0][i] = fmaf(wvv.x, xv, acc[0][i]);
      acc[1][i] = fmaf(wvv.y, xv, acc[1][i]);
      acc[2][i] = fmaf(wvv.z, xv, acc[2][i]);
      acc[3][i] = fmaf(wvv.w, xv, acc[3][i]);
    }
  }
  const float gm = gamma[0];
#pragma unroll
  for (int j = 0; j < 4; ++j) {
    const int o = o0 + j;
    const float bj = bias[o];
#pragma unroll
    for (int i = 0; i < 2; ++i) {
      const size_t idx =
          (size_t)n * (CC * PQ) + (size_t)o * PQ + (p0 + pl0 + i);
      out[idx] = fmaf(gm, acc[j][i] + bj, x_in[idx]);
    }
  }
}

// ---------------------------------------------------------------------------
extern "C" void kernel_launch(void* const* d_in, const int* in_sizes, int n_in,
                              void* d_out, int out_size, void* d_ws,
                              size_t ws_size, hipStream_t stream) {
  const float* x = (const float*)d_in[0];
  const float* q_w = (const float*)d_in[1];
  const float* k_w = (const float*)d_in[2];
  const float* v_w = (const float*)d_in[3];
  const float* fcx_w = (const float*)d_in[4];
  const float* fcy_w = (const float*)d_in[5];
  const float* ab = (const float*)d_in[6];
  const float* gb = (const float*)d_in[7];
  const float* proj_w = (const float*)d_in[8];
  const float* proj_b = (const float*)d_in[9];
  const float* gamma = (const float*)d_in[10];
  float* out = (float*)d_out;

  float* ws = (float*)d_ws;
  float* att = ws;                       // 2*256*4096 = 2,097,152 f
  float* qwt = att + 2097152;            // 65,536 f
  float* kwt = qwt + 65536;
  float* vwt = kwt + 65536;
  float* pwt = vwt + 65536;
  float* EX = pwt + 65536;               // 16*4096*36 = 2,359,296 f
  float* EY = EX + 2359296;              // 16*4096*20 = 1,310,720 f
  __hip_bfloat16* pembx_b = (__hip_bfloat16*)(EY + 1310720);  // 32,256
  __hip_bfloat16* pemby_b = pembx_b + 32256;                  // 32,256
  __hip_bfloat16* qab_b = pemby_b + 32256;   // 2*8*4096*32 = 2,097,152
  __hip_bfloat16* qgb_b = qab_b + 2097152;   // 2,097,152
  __hip_bfloat16* k_lb = qgb_b + 2097152;    //   524,288
  __hip_bfloat16* v_t = k_lb + 524288;       //   524,288

  transpose4_kernel<<<dim3(256, 4), 256, 0, stream>>>(q_w, k_w, v_w, proj_w,
                                                      qwt, kwt, vwt, pwt);
  posfeat_kernel<<<dim3(126, 2), 256, 0, stream>>>(fcx_w, fcy_w, pembx_b,
                                                   pemby_b);
  proj_kernel<0><<<dim3(128, 2, 4), 256, 0, stream>>>(
      x, qwt, nullptr, (void*)qab_b, (void*)qgb_b, ab, gb);
  proj_kernel<1><<<dim3(128, 2, 2), 256, 0, stream>>>(
      x, kwt, vwt, (void*)k_lb, (void*)v_t, nullptr, nullptr);
  exy_kernel<0><<<dim3(64, 16), 256, 0, stream>>>(qgb_b, pembx_b, EX);
  exy_kernel<1><<<dim3(64, 16), 256, 0, stream>>>(qgb_b, pemby_b, EY);
  attn_mfma_kernel<<<dim3(64, 16), 256, 0, stream>>>(qab_b, k_lb, v_t, EX, EY,
                                                     att);
  proj_out_kernel<<<dim3(128, 2, 4), 256, 0, stream>>>(att, pwt, proj_b,
                                                       gamma, x, out);
}

// Round 10
// 135.131 us; speedup vs baseline: 7.0581x; 1.1292x over previous
//
#include <hip/hip_runtime.h>
#include <hip/hip_bf16.h>
#include <math.h>

// Problem sizes (fixed by the reference)
#define NB   2
#define CC   256
#define PQ   4096   // 64*64 queries per image
#define PKV  1024   // 32*32 kv per image

#define NF (-INFINITY)
#define M0 24.0f    // fixed softmax offset (baked into EX; |e| << 80)
#define EXSTRIDE 36
#define EYSTRIDE 20

typedef __attribute__((ext_vector_type(8))) short short8;
typedef __attribute__((ext_vector_type(4))) float f32x4;

// ---------------------------------------------------------------------------
// Transpose three 256x256 weight matrices to fp32 Wt[c][o] (VALU proj path)
// ---------------------------------------------------------------------------
__global__ __launch_bounds__(256) void transpose3_kernel(
    const float* __restrict__ a, const float* __restrict__ b,
    const float* __restrict__ c, float* __restrict__ ta,
    float* __restrict__ tb, float* __restrict__ tc) {
  const int which = blockIdx.y;
  const float* src = (which == 0) ? a : (which == 1) ? b : c;
  float* dst = (which == 0) ? ta : (which == 1) ? tb : tc;
  const int idx = blockIdx.x * 256 + threadIdx.x;   // 65536 total
  const int o = idx >> 8, ch = idx & 255;
  dst[ch * 256 + o] = src[idx];
}

// ---------------------------------------------------------------------------
// proj_w fp32 -> bf16, same [o][c] layout (MFMA A-frag reads rows)
// ---------------------------------------------------------------------------
__global__ __launch_bounds__(256) void wconv1_kernel(
    const float* __restrict__ src, __hip_bfloat16* __restrict__ dst) {
  const int i = blockIdx.x * 256 + threadIdx.x;   // 16384 float4 groups
  const float4 v = reinterpret_cast<const float4*>(src)[i];
  short4 s;
  s.x = __builtin_bit_cast(short, __float2bfloat16(v.x));
  s.y = __builtin_bit_cast(short, __float2bfloat16(v.y));
  s.z = __builtin_bit_cast(short, __float2bfloat16(v.z));
  s.w = __builtin_bit_cast(short, __float2bfloat16(v.w));
  reinterpret_cast<short4*>(dst)[i] = s;
}

// ---------------------------------------------------------------------------
// Positional feature tables (bf16), deduplicated over diff d = i - 2k
// ---------------------------------------------------------------------------
__global__ __launch_bounds__(256) void posfeat_kernel(
    const float* __restrict__ fcx, const float* __restrict__ fcy,
    __hip_bfloat16* __restrict__ pembx_b, __hip_bfloat16* __restrict__ pemby_b) {
  const int dd = blockIdx.x;          // 0..125 -> diff = dd - 62
  const int which = blockIdx.y;
  const float* FC = which ? fcy : fcx;
  __hip_bfloat16* OUT = which ? pemby_b : pembx_b;
  __shared__ __align__(16) float feat[128];
  const int tid = threadIdx.x;
  if (tid < 64) {
    const float diff = (float)(dd - 62);
    const float dm = powf(1000.f, (float)tid * (1.f / 64.f));
    const float aa = diff / dm;
    feat[tid] = sinf(aa);
    feat[tid + 64] = cosf(aa);
  }
  __syncthreads();
  const float4* row4 = reinterpret_cast<const float4*>(FC + tid * 128);
  const float4* f4 = reinterpret_cast<const float4*>(feat);
  float s0 = 0.f, s1 = 0.f, s2 = 0.f, s3 = 0.f;
#pragma unroll
  for (int f = 0; f < 32; ++f) {
    const float4 fv = f4[f];
    const float4 rv = row4[f];
    s0 = fmaf(fv.x, rv.x, s0);
    s1 = fmaf(fv.y, rv.y, s1);
    s2 = fmaf(fv.z, rv.z, s2);
    s3 = fmaf(fv.w, rv.w, s3);
  }
  const float s = ((s0 + s1) + (s2 + s3)) * 0.70710678118654752440f;
  OUT[(size_t)dd * 256 + tid] = __float2bfloat16(s);
}

// ---------------------------------------------------------------------------
// QKV projection (R9-proven, unchanged).
// ---------------------------------------------------------------------------
template <int MODE>
__global__ __launch_bounds__(256) void proj_kernel(
    const float* __restrict__ X, const float* __restrict__ WtA,
    const float* __restrict__ WtB, void* __restrict__ outA,
    void* __restrict__ outB, const float* __restrict__ bA,
    const float* __restrict__ bB) {
  constexpr int P = (MODE == 0) ? PQ : PKV;
  const int n = blockIdx.y;
  const float* Wt = WtA;
  void* out = outA;
  bool isV = false;
  if (MODE == 1 && blockIdx.z == 1) { Wt = WtB; out = outB; isV = true; }
  int p0, q4;
  if (MODE == 0) {
    p0 = blockIdx.x * 32;
    q4 = blockIdx.z;
  } else {
    p0 = (blockIdx.x >> 2) * 32;
    q4 = blockIdx.x & 3;
  }
  const float* Xn = X + (size_t)n * (CC * PQ);
  __shared__ float xs[256][32];
  const int tid = threadIdx.x;
  {
    const int pl = tid & 31;
    const int c0 = tid >> 5;  // 0..7
    const int p = p0 + pl;
    const int gp = (MODE == 0) ? p : ((p >> 5) * 128 + (p & 31) * 2);
#pragma unroll
    for (int i = 0; i < 32; ++i) {
      const int c = i * 8 + c0;
      xs[c][pl] = Xn[(size_t)c * PQ + gp];
    }
  }
  __syncthreads();
  const int og = tid & 15;   // 16 output groups of 4 -> 64 outputs
  const int pg = tid >> 4;   // 16 pixel groups of 2  -> 32 px
  const int o0 = q4 * 64 + og * 4;
  const int pl0 = pg * 2;
  float acc[4][2];
#pragma unroll
  for (int j = 0; j < 4; ++j)
#pragma unroll
    for (int i = 0; i < 2; ++i) acc[j][i] = 0.f;
#pragma unroll 4
  for (int c = 0; c < 256; ++c) {
    const float4 wv = *reinterpret_cast<const float4*>(Wt + c * 256 + o0);
#pragma unroll
    for (int i = 0; i < 2; ++i) {
      const float xv = xs[c][pl0 + i];
      acc[0][i] = fmaf(wv.x, xv, acc[0][i]);
      acc[1][i] = fmaf(wv.y, xv, acc[1][i]);
      acc[2][i] = fmaf(wv.z, xv, acc[2][i]);
      acc[3][i] = fmaf(wv.w, xv, acc[3][i]);
    }
  }
#pragma unroll
  for (int j = 0; j < 4; ++j) {
    const int o = o0 + j;
    const int head = o >> 5, dd = o & 31;
#pragma unroll
    for (int i = 0; i < 2; ++i) {
      const int p = p0 + pl0 + i;
      const size_t idx = ((size_t)((n * 8 + head) * P + p)) * 32 + dd;
      if (MODE == 0) {
        ((__hip_bfloat16*)outA)[idx] = __float2bfloat16(acc[j][i] + bA[o]);
        ((__hip_bfloat16*)outB)[idx] = __float2bfloat16(acc[j][i] + bB[o]);
      } else if (!isV) {
        ((__hip_bfloat16*)out)[idx] = __float2bfloat16(acc[j][i]);
      } else {
        ((__hip_bfloat16*)out)[((size_t)((n * 8 + head)) * 32 + dd) * PKV + p] =
            __float2bfloat16(acc[j][i]);
      }
    }
  }
}

// ---------------------------------------------------------------------------
// Positional energy tables via MFMA (R9-proven, unchanged).
// ---------------------------------------------------------------------------
template <int MODE>
__global__ __launch_bounds__(256) void exy_kernel(
    const __hip_bfloat16* __restrict__ qgb_b,
    const __hip_bfloat16* __restrict__ pemb_b, float* __restrict__ OUT) {
  const int i = blockIdx.x;       // x (MODE0) or y (MODE1)
  const int g = blockIdx.y;
  const int head = g & 7;
  const int wv = threadIdx.x >> 6;
  const int l = threadIdx.x & 63;
  const int lc = l & 15, lq = l >> 4;

  const int rowi = wv * 16 + lc;  // y (MODE0) or x (MODE1)
  const int p = (MODE == 0) ? rowi * 64 + i : i * 64 + rowi;
  const short8 a = *reinterpret_cast<const short8*>(
      (const short*)qgb_b + ((size_t)g * PQ + p) * 32 + 8 * lq);

  int drow0, drow1;
  if (MODE == 0) {
    drow0 = i - 2 * lc + 62;
    drow1 = i - 2 * (lc + 16) + 62;
  } else {
    const int lo_y = max((i - 16) >> 1, 0);
    drow0 = i - 2 * (lo_y + lc) + 62;
    drow1 = i - 2 * (lo_y + lc + 16) + 62;
  }
  const short8 b0 = *reinterpret_cast<const short8*>(
      (const short*)pemb_b + (size_t)drow0 * 256 + head * 32 + 8 * lq);
  const short8 b1 = *reinterpret_cast<const short8*>(
      (const short*)pemb_b + (size_t)drow1 * 256 + head * 32 + 8 * lq);

  const f32x4 zero = {0.f, 0.f, 0.f, 0.f};
  const f32x4 c0 = __builtin_amdgcn_mfma_f32_16x16x32_bf16(a, b0, zero, 0, 0, 0);
  const f32x4 c1 = __builtin_amdgcn_mfma_f32_16x16x32_bf16(a, b1, zero, 0, 0, 0);

#pragma unroll
  for (int r = 0; r < 4; ++r) {
    const int rowr = wv * 16 + 4 * lq + r;
    const int pr = (MODE == 0) ? rowr * 64 + i : i * 64 + rowr;
    if (MODE == 0) {
      const int lox = max((i - 16) >> 1, 0);
      const int hix = min(((i + 17) >> 1) + 1, 32);
      float* o = OUT + ((size_t)g * PQ + pr) * EXSTRIDE;
      o[lc] = (lc >= lox && lc < hix) ? (c0[r] - M0) : -1e30f;
      o[16 + lc] = (lc + 16 >= lox && lc + 16 < hix) ? (c1[r] - M0) : -1e30f;
      if (lc < 4) o[32 + lc] = -1e30f;
    } else {
      float* o = OUT + ((size_t)g * PQ + pr) * EYSTRIDE;
      o[lc] = c0[r];
      if (lc < 4) o[16 + lc] = c1[r];
    }
  }
}

// ---------------------------------------------------------------------------
// MFMA local-window attention (R9-proven, unchanged; fp32 att store).
// ---------------------------------------------------------------------------
__global__ __launch_bounds__(256) void attn_mfma_kernel(
    const __hip_bfloat16* __restrict__ qab_b,
    const __hip_bfloat16* __restrict__ k_lb,
    const __hip_bfloat16* __restrict__ v_t, const float* __restrict__ EX,
    const float* __restrict__ EY, float* __restrict__ att) {
  const int g = blockIdx.y;    // n*8 + head
  const int bx = blockIdx.x & 3;   // x-tile of 16
  const int by = blockIdx.x >> 2;  // y-tile of 4 rows
  const int tx = bx * 16;
  const int wv = threadIdx.x >> 6;
  const int y = by * 4 + wv;
  const int l = threadIdx.x & 63;
  const int lc = l & 15;   // col lane (q for S^T / vd for O)
  const int lq = l >> 4;   // quarter

  __shared__ float eybuf[4][EYSTRIDE][16];  // [wave][t][q]

  const int KLO = max((tx - 16) >> 1, 0);
  const int lo_y = max((y - 16) >> 1, 0);
  const int hi_y = min(((y + 17) >> 1) + 1, 32);
  const int NKY = hi_y - lo_y;

  const int xq = tx + lc;
  const int pq_ = y * 64 + xq;

  // Qa B-frag: lane holds Qa[d=8lq+j][q=lc]
  const short8 qa = *reinterpret_cast<const short8*>(
      (const short*)qab_b + ((size_t)g * PQ + pq_) * 32 + 8 * lq);

  // per-lane loop-invariant ex registers (mask, M0, x-positional term baked)
  const float* exr = EX + ((size_t)g * PQ + pq_) * EXSTRIDE;
  float exC0[4], exC1[4];
#pragma unroll
  for (int r = 0; r < 4; ++r) {
    exC0[r] = exr[KLO + 4 * lq + r];
    exC1[r] = exr[min(KLO + 16 + 4 * lq + r, 35)];
  }

  // ey -> LDS ([t][q] layout for conflict-free loop reads)
  {
    const float* eyr = EY + ((size_t)g * PQ + pq_) * EYSTRIDE;
    const float4 e4 = *reinterpret_cast<const float4*>(eyr + 4 * lq);
#pragma unroll
    for (int j = 0; j < 4; ++j) eybuf[wv][4 * lq + j][lc] = e4[j];
    if (lq == 0) {
      const float4 e4b = *reinterpret_cast<const float4*>(eyr + 16);
#pragma unroll
      for (int j = 0; j < 4; ++j) eybuf[wv][16 + j][lc] = e4b[j];
    }
  }

  const __hip_bfloat16* kb =
      k_lb + ((size_t)g * PKV + (size_t)lo_y * 32) * 32;
  const __hip_bfloat16* kb0 = kb + (KLO + lc) * 32 + 8 * lq;
  const __hip_bfloat16* kb1 = kb + min(KLO + 16 + lc, 31) * 32 + 8 * lq;
  const __hip_bfloat16* vb0 =
      v_t + ((size_t)g * 32 + lc) * PKV + (size_t)lo_y * 32 + KLO + 8 * lq;
  const __hip_bfloat16* vb1 = vb0 + 16 * PKV;

  f32x4 acc0 = {0.f, 0.f, 0.f, 0.f};
  f32x4 acc1 = {0.f, 0.f, 0.f, 0.f};
  float lp = 0.f;
  const int srcA = lc + ((l & 16) << 1);  // lane lc + 32*(lq&1)
  const int srcB = srcA + 16;
  const bool hiL = (l & 32) != 0;

#pragma unroll 1
  for (int t = 0; t < NKY; ++t) {
    const short8 k0 = *reinterpret_cast<const short8*>(kb0 + t * 1024);
    const short8 k1 = *reinterpret_cast<const short8*>(kb1 + t * 1024);
    const short8 v0 = *reinterpret_cast<const short8*>(vb0 + t * 32);
    const short8 v1 = *reinterpret_cast<const short8*>(vb1 + t * 32);
    const f32x4 zero = {0.f, 0.f, 0.f, 0.f};
    // S^T tiles: rows kx_local = 4*lq + r, cols q = lc
    const f32x4 s0 = __builtin_amdgcn_mfma_f32_16x16x32_bf16(k0, qa, zero, 0, 0, 0);
    const f32x4 s1 = __builtin_amdgcn_mfma_f32_16x16x32_bf16(k1, qa, zero, 0, 0, 0);
    const float eyC = eybuf[wv][t][lc];
    float p0[4], p1[4];
#pragma unroll
    for (int r = 0; r < 4; ++r) {
      p0[r] = __expf(s0[r] + exC0[r] + eyC);   // masked: exC=-1e30 -> 0
      p1[r] = __expf(s1[r] + exC1[r] + eyC);
    }
    lp += ((p0[0] + p0[1]) + (p0[2] + p0[3])) +
          ((p1[0] + p1[1]) + (p1[2] + p1[3]));
    int w00, w01, w10, w11;
    asm("v_cvt_pk_bf16_f32 %0, %1, %2" : "=v"(w00) : "v"(p0[0]), "v"(p0[1]));
    asm("v_cvt_pk_bf16_f32 %0, %1, %2" : "=v"(w01) : "v"(p0[2]), "v"(p0[3]));
    asm("v_cvt_pk_bf16_f32 %0, %1, %2" : "=v"(w10) : "v"(p1[0]), "v"(p1[1]));
    asm("v_cvt_pk_bf16_f32 %0, %1, %2" : "=v"(w11) : "v"(p1[2]), "v"(p1[3]));
    const int a0 = __shfl(w00, srcA, 64), b0 = __shfl(w10, srcA, 64);
    const int a1 = __shfl(w01, srcA, 64), b1 = __shfl(w11, srcA, 64);
    const int a2 = __shfl(w00, srcB, 64), b2 = __shfl(w10, srcB, 64);
    const int a3 = __shfl(w01, srcB, 64), b3 = __shfl(w11, srcB, 64);
    int4 pw;
    pw.x = hiL ? b0 : a0;
    pw.y = hiL ? b1 : a1;
    pw.z = hiL ? b2 : a2;
    pw.w = hiL ? b3 : a3;
    const short8 pf = __builtin_bit_cast(short8, pw);
    acc0 = __builtin_amdgcn_mfma_f32_16x16x32_bf16(pf, v0, acc0, 0, 0, 0);
    acc1 = __builtin_amdgcn_mfma_f32_16x16x32_bf16(pf, v1, acc1, 0, 0, 0);
  }

  // l: sum over the 4 lq groups -> every lane holds L[q=lc]
  lp += __shfl_xor(lp, 16);
  lp += __shfl_xor(lp, 32);
  const float invall = 1.f / lp;
#pragma unroll
  for (int r = 0; r < 4; ++r) {
    const float inv = __shfl(invall, 4 * lq + r, 16);  // L for q = 4lq+r
    const int p = y * 64 + tx + 4 * lq + r;
    att[((size_t)g * 32 + lc) * PQ + p] = acc0[r] * inv;
    att[((size_t)g * 32 + 16 + lc) * PQ + p] = acc1[r] * inv;
  }
}

// ---------------------------------------------------------------------------
// att fp32 [g*32+vd][p]  ->  attb bf16 [n][p][c=hd*32+vd]  (LDS tile xpose)
// grid (64 p-tiles, 16 g), 256 threads. Coalesced reads; 16B row writes.
// ---------------------------------------------------------------------------
__global__ __launch_bounds__(256) void att2b_kernel(
    const float* __restrict__ att, __hip_bfloat16* __restrict__ attb) {
  const int g = blockIdx.y;
  const int nImg = g >> 3, hd = g & 7;
  const int p0 = blockIdx.x * 64;
  const int tid = threadIdx.x;
  __shared__ float t[32][65];
  {
    const int pl = tid & 63;
    const int v0 = (tid >> 6) * 8;
#pragma unroll
    for (int j = 0; j < 8; ++j)
      t[v0 + j][pl] = att[((size_t)g * 32 + v0 + j) * PQ + p0 + pl];
  }
  __syncthreads();
  const int pl = tid & 63;
  const int vq = tid >> 6;
  short8 s;
#pragma unroll
  for (int j = 0; j < 8; ++j)
    s[j] = __builtin_bit_cast(short, __float2bfloat16(t[vq * 8 + j][pl]));
  *reinterpret_cast<short8*>(
      (short*)attb + ((size_t)nImg * PQ + p0 + pl) * 256 + hd * 32 + vq * 8) = s;
}

// ---------------------------------------------------------------------------
// MFMA GEMM: output projection + bias + gamma + residual (R8 formulation).
// C[o][p] = sum_c pw[o][c] * attb[n][p][c]; out = gamma*(C+pb) + x.
// ---------------------------------------------------------------------------
__global__ __launch_bounds__(256) void gemm_out_kernel(
    const __hip_bfloat16* __restrict__ attb,
    const __hip_bfloat16* __restrict__ pw, const float* __restrict__ pb,
    const float* __restrict__ gamma, const float* __restrict__ x_in,
    float* __restrict__ out) {
  const int p0 = blockIdx.x * 64;
  const int o0 = blockIdx.y * 64;
  const int n = blockIdx.z;
  const int tid = threadIdx.x;
  const int wv = tid >> 6, l = tid & 63, lc = l & 15, lq = l >> 4;
  // A-frag: A[m = o_local = lc][k = c = 8*lq + j + 32*kt]
  const short* ar =
      (const short*)pw + ((size_t)(o0 + wv * 16 + lc)) * 256 + 8 * lq;
  // B-frags: B[k = c][n = p_local = lc], 4 n-tiles of 16
  const short* bbase = (const short*)attb + ((size_t)n * PQ + p0) * 256 + 8 * lq;
  const short* b0p = bbase + (size_t)(0 + lc) * 256;
  const short* b1p = bbase + (size_t)(16 + lc) * 256;
  const short* b2p = bbase + (size_t)(32 + lc) * 256;
  const short* b3p = bbase + (size_t)(48 + lc) * 256;
  f32x4 acc0 = {0.f, 0.f, 0.f, 0.f};
  f32x4 acc1 = {0.f, 0.f, 0.f, 0.f};
  f32x4 acc2 = {0.f, 0.f, 0.f, 0.f};
  f32x4 acc3 = {0.f, 0.f, 0.f, 0.f};
#pragma unroll
  for (int kt = 0; kt < 8; ++kt) {
    const short8 af = *reinterpret_cast<const short8*>(ar + kt * 32);
    acc0 = __builtin_amdgcn_mfma_f32_16x16x32_bf16(
        af, *reinterpret_cast<const short8*>(b0p + kt * 32), acc0, 0, 0, 0);
    acc1 = __builtin_amdgcn_mfma_f32_16x16x32_bf16(
        af, *reinterpret_cast<const short8*>(b1p + kt * 32), acc1, 0, 0, 0);
    acc2 = __builtin_amdgcn_mfma_f32_16x16x32_bf16(
        af, *reinterpret_cast<const short8*>(b2p + kt * 32), acc2, 0, 0, 0);
    acc3 = __builtin_amdgcn_mfma_f32_16x16x32_bf16(
        af, *reinterpret_cast<const short8*>(b3p + kt * 32), acc3, 0, 0, 0);
  }
  const float gm = gamma[0];
#pragma unroll
  for (int r = 0; r < 4; ++r) {
    const int o = o0 + wv * 16 + 4 * lq + r;   // C row = 4*lq + r
    const float bo = pb[o];
    const size_t obase = ((size_t)n * 256 + o) * PQ;
    const size_t i0 = obase + (p0 + 0 + lc);
    const size_t i1 = obase + (p0 + 16 + lc);
    const size_t i2 = obase + (p0 + 32 + lc);
    const size_t i3 = obase + (p0 + 48 + lc);
    out[i0] = fmaf(gm, acc0[r] + bo, x_in[i0]);
    out[i1] = fmaf(gm, acc1[r] + bo, x_in[i1]);
    out[i2] = fmaf(gm, acc2[r] + bo, x_in[i2]);
    out[i3] = fmaf(gm, acc3[r] + bo, x_in[i3]);
  }
}

// ---------------------------------------------------------------------------
extern "C" void kernel_launch(void* const* d_in, const int* in_sizes, int n_in,
                              void* d_out, int out_size, void* d_ws,
                              size_t ws_size, hipStream_t stream) {
  const float* x = (const float*)d_in[0];
  const float* q_w = (const float*)d_in[1];
  const float* k_w = (const float*)d_in[2];
  const float* v_w = (const float*)d_in[3];
  const float* fcx_w = (const float*)d_in[4];
  const float* fcy_w = (const float*)d_in[5];
  const float* ab = (const float*)d_in[6];
  const float* gb = (const float*)d_in[7];
  const float* proj_w = (const float*)d_in[8];
  const float* proj_b = (const float*)d_in[9];
  const float* gamma = (const float*)d_in[10];
  float* out = (float*)d_out;

  float* ws = (float*)d_ws;
  float* att = ws;                       // 2*256*4096 = 2,097,152 f
  float* qwt = att + 2097152;            // 65,536 f
  float* kwt = qwt + 65536;
  float* vwt = kwt + 65536;
  float* EX = vwt + 65536;               // 16*4096*36 = 2,359,296 f
  float* EY = EX + 2359296;              // 16*4096*20 = 1,310,720 f
  __hip_bfloat16* pembx_b = (__hip_bfloat16*)(EY + 1310720);  // 32,256
  __hip_bfloat16* pemby_b = pembx_b + 32256;                  // 32,256
  __hip_bfloat16* qab_b = pemby_b + 32256;   // 2*8*4096*32 = 2,097,152
  __hip_bfloat16* qgb_b = qab_b + 2097152;   // 2,097,152
  __hip_bfloat16* k_lb = qgb_b + 2097152;    //   524,288
  __hip_bfloat16* v_t = k_lb + 524288;       //   524,288
  __hip_bfloat16* pw_b = v_t + 524288;       //    65,536
  __hip_bfloat16* attb = pw_b + 65536;       // 2,097,152
  // total ~ 39 MB

  transpose3_kernel<<<dim3(256, 3), 256, 0, stream>>>(q_w, k_w, v_w, qwt, kwt,
                                                      vwt);
  wconv1_kernel<<<dim3(64), 256, 0, stream>>>(proj_w, pw_b);
  posfeat_kernel<<<dim3(126, 2), 256, 0, stream>>>(fcx_w, fcy_w, pembx_b,
                                                   pemby_b);
  proj_kernel<0><<<dim3(128, 2, 4), 256, 0, stream>>>(
      x, qwt, nullptr, (void*)qab_b, (void*)qgb_b, ab, gb);
  proj_kernel<1><<<dim3(128, 2, 2), 256, 0, stream>>>(
      x, kwt, vwt, (void*)k_lb, (void*)v_t, nullptr, nullptr);
  exy_kernel<0><<<dim3(64, 16), 256, 0, stream>>>(qgb_b, pembx_b, EX);
  exy_kernel<1><<<dim3(64, 16), 256, 0, stream>>>(qgb_b, pemby_b, EY);
  attn_mfma_kernel<<<dim3(64, 16), 256, 0, stream>>>(qab_b, k_lb, v_t, EX, EY,
                                                     att);
  att2b_kernel<<<dim3(64, 16), 256, 0, stream>>>(att, attb);
  gemm_out_kernel<<<dim3(64, 4, 2), 256, 0, stream>>>(attb, pw_b, proj_b,
                                                      gamma, x, out);
}

// Round 11
// 100.904 us; speedup vs baseline: 9.4523x; 1.3392x over previous
//
#include <hip/hip_runtime.h>
#include <hip/hip_bf16.h>
#include <math.h>

// Problem sizes (fixed by the reference)
#define NB   2
#define CC   256
#define PQ   4096   // 64*64 queries per image
#define PKV  1024   // 32*32 kv per image

#define NF (-INFINITY)
#define M0 24.0f    // fixed softmax offset (baked into EX; |e| << 80)
#define EXSTRIDE 36
#define EYSTRIDE 20

typedef __attribute__((ext_vector_type(8))) short short8;
typedef __attribute__((ext_vector_type(4))) float f32x4;

// ---------------------------------------------------------------------------
// Weights fp32 -> bf16, same [o][c] row-major layout (MFMA A-frag reads rows)
// ---------------------------------------------------------------------------
__global__ __launch_bounds__(256) void wconv4_kernel(
    const float* __restrict__ a, const float* __restrict__ b,
    const float* __restrict__ c, const float* __restrict__ d,
    __hip_bfloat16* __restrict__ ta, __hip_bfloat16* __restrict__ tb,
    __hip_bfloat16* __restrict__ tc, __hip_bfloat16* __restrict__ td) {
  const int which = blockIdx.y;
  const float* src = (which == 0) ? a : (which == 1) ? b : (which == 2) ? c : d;
  __hip_bfloat16* dst = (which == 0) ? ta : (which == 1) ? tb
                        : (which == 2) ? tc : td;
  const int i = blockIdx.x * 256 + threadIdx.x;   // 16384 float4 groups
  const float4 v = reinterpret_cast<const float4*>(src)[i];
  short4 s;
  s.x = __builtin_bit_cast(short, __float2bfloat16(v.x));
  s.y = __builtin_bit_cast(short, __float2bfloat16(v.y));
  s.z = __builtin_bit_cast(short, __float2bfloat16(v.z));
  s.w = __builtin_bit_cast(short, __float2bfloat16(v.w));
  reinterpret_cast<short4*>(dst)[i] = s;
}

// ---------------------------------------------------------------------------
// x fp32 [n][c][p] -> bf16 pixel-major xb[n][p][c]  (64x64 LDS tile)
// grid (64 rows, 4 c-tiles, 2 n)
// ---------------------------------------------------------------------------
__global__ __launch_bounds__(256) void xpose_kernel(
    const float* __restrict__ x, __hip_bfloat16* __restrict__ xb) {
  const int p0 = blockIdx.x * 64;
  const int c0 = blockIdx.y * 64;
  const int n = blockIdx.z;
  __shared__ float t[64][65];
  const int tid = threadIdx.x;
  {
    const int pl = tid & 63, cg = tid >> 6;
#pragma unroll
    for (int i = 0; i < 16; ++i) {
      const int cl = cg * 16 + i;
      t[cl][pl] = x[((size_t)n * 256 + c0 + cl) * PQ + p0 + pl];
    }
  }
  __syncthreads();
  const int cl = tid & 63;
#pragma unroll
  for (int j = 0; j < 16; ++j) {
    const int pl = (tid >> 6) + 4 * j;
    ((__hip_bfloat16*)xb)[((size_t)n * PQ + p0 + pl) * 256 + c0 + cl] =
        __float2bfloat16(t[cl][pl]);
  }
}

// ---------------------------------------------------------------------------
// Positional feature tables (bf16), deduplicated over diff d = i - 2k
// ---------------------------------------------------------------------------
__global__ __launch_bounds__(256) void posfeat_kernel(
    const float* __restrict__ fcx, const float* __restrict__ fcy,
    __hip_bfloat16* __restrict__ pembx_b, __hip_bfloat16* __restrict__ pemby_b) {
  const int dd = blockIdx.x;          // 0..125 -> diff = dd - 62
  const int which = blockIdx.y;
  const float* FC = which ? fcy : fcx;
  __hip_bfloat16* OUT = which ? pemby_b : pembx_b;
  __shared__ __align__(16) float feat[128];
  const int tid = threadIdx.x;
  if (tid < 64) {
    const float diff = (float)(dd - 62);
    const float dm = powf(1000.f, (float)tid * (1.f / 64.f));
    const float aa = diff / dm;
    feat[tid] = sinf(aa);
    feat[tid + 64] = cosf(aa);
  }
  __syncthreads();
  const float4* row4 = reinterpret_cast<const float4*>(FC + tid * 128);
  const float4* f4 = reinterpret_cast<const float4*>(feat);
  float s0 = 0.f, s1 = 0.f, s2 = 0.f, s3 = 0.f;
#pragma unroll
  for (int f = 0; f < 32; ++f) {
    const float4 fv = f4[f];
    const float4 rv = row4[f];
    s0 = fmaf(fv.x, rv.x, s0);
    s1 = fmaf(fv.y, rv.y, s1);
    s2 = fmaf(fv.z, rv.z, s2);
    s3 = fmaf(fv.w, rv.w, s3);
  }
  const float s = ((s0 + s1) + (s2 + s3)) * 0.70710678118654752440f;
  OUT[(size_t)dd * 256 + tid] = __float2bfloat16(s);
}

// ---------------------------------------------------------------------------
// MFMA GEMM: Q projection (gemm_out-proven formulation).
// C[o][p] = sum_c qw[o][c]*xb[n][p][c]; outputs qab=C+ab, qgb=C+gb (bf16,
// [g][p][dd]).  grid (64 p-tiles, 4 o-tiles, 2 n); block 4 waves.
// ---------------------------------------------------------------------------
__global__ __launch_bounds__(256) void gemm_q_kernel(
    const __hip_bfloat16* __restrict__ xb,
    const __hip_bfloat16* __restrict__ qw, const float* __restrict__ ab,
    const float* __restrict__ gb, __hip_bfloat16* __restrict__ qab,
    __hip_bfloat16* __restrict__ qgb) {
  const int p0 = blockIdx.x * 64;
  const int o0 = blockIdx.y * 64;
  const int n = blockIdx.z;
  const int tid = threadIdx.x;
  const int wv = tid >> 6, l = tid & 63, lc = l & 15, lq = l >> 4;
  const short* ar =
      (const short*)qw + ((size_t)(o0 + wv * 16 + lc)) * 256 + 8 * lq;
  const short* bbase = (const short*)xb + ((size_t)n * PQ + p0) * 256 + 8 * lq;
  const short* b0p = bbase + (size_t)(0 + lc) * 256;
  const short* b1p = bbase + (size_t)(16 + lc) * 256;
  const short* b2p = bbase + (size_t)(32 + lc) * 256;
  const short* b3p = bbase + (size_t)(48 + lc) * 256;
  f32x4 acc0 = {0.f, 0.f, 0.f, 0.f};
  f32x4 acc1 = {0.f, 0.f, 0.f, 0.f};
  f32x4 acc2 = {0.f, 0.f, 0.f, 0.f};
  f32x4 acc3 = {0.f, 0.f, 0.f, 0.f};
#pragma unroll
  for (int kt = 0; kt < 8; ++kt) {
    const short8 af = *reinterpret_cast<const short8*>(ar + kt * 32);
    acc0 = __builtin_amdgcn_mfma_f32_16x16x32_bf16(
        af, *reinterpret_cast<const short8*>(b0p + kt * 32), acc0, 0, 0, 0);
    acc1 = __builtin_amdgcn_mfma_f32_16x16x32_bf16(
        af, *reinterpret_cast<const short8*>(b1p + kt * 32), acc1, 0, 0, 0);
    acc2 = __builtin_amdgcn_mfma_f32_16x16x32_bf16(
        af, *reinterpret_cast<const short8*>(b2p + kt * 32), acc2, 0, 0, 0);
    acc3 = __builtin_amdgcn_mfma_f32_16x16x32_bf16(
        af, *reinterpret_cast<const short8*>(b3p + kt * 32), acc3, 0, 0, 0);
  }
#pragma unroll
  for (int r = 0; r < 4; ++r) {
    const int o = o0 + wv * 16 + 4 * lq + r;   // C row = 4*lq + r
    const float abo = ab[o], gbo = gb[o];
    const int head = o >> 5, dd = o & 31;
    const size_t gbase = (size_t)(n * 8 + head) * PQ;
    const float a_[4] = {acc0[r], acc1[r], acc2[r], acc3[r]};
#pragma unroll
    for (int nf = 0; nf < 4; ++nf) {
      const int p = p0 + 16 * nf + lc;
      const size_t idx = (gbase + p) * 32 + dd;
      qab[idx] = __float2bfloat16(a_[nf] + abo);
      qgb[idx] = __float2bfloat16(a_[nf] + gbo);
    }
  }
}

// ---------------------------------------------------------------------------
// MFMA GEMM: K/V projection over 1024 kv pixels (strided gather from xb).
// z = n + 2*isV. K -> [g][p][dd]; V -> transposed [g*32+dd][p].
// grid (16 p-tiles, 4 o-tiles, 4)
// ---------------------------------------------------------------------------
__global__ __launch_bounds__(256) void gemm_kv_kernel(
    const __hip_bfloat16* __restrict__ xb,
    const __hip_bfloat16* __restrict__ kw, const __hip_bfloat16* __restrict__ vw,
    __hip_bfloat16* __restrict__ k_lb, __hip_bfloat16* __restrict__ v_t) {
  const int p0 = blockIdx.x * 64;
  const int o0 = blockIdx.y * 64;
  const int n = blockIdx.z & 1;
  const bool isV = (blockIdx.z >> 1) != 0;
  const __hip_bfloat16* W = isV ? vw : kw;
  const int tid = threadIdx.x;
  const int wv = tid >> 6, l = tid & 63, lc = l & 15, lq = l >> 4;
  const short* ar =
      (const short*)W + ((size_t)(o0 + wv * 16 + lc)) * 256 + 8 * lq;
  // kv pixel pk -> image pixel gp = (pk>>5)*128 + (pk&31)*2
  const short* bb = (const short*)xb + (size_t)n * PQ * 256 + 8 * lq;
  const int pk0 = p0 + 0 + lc, pk1 = p0 + 16 + lc;
  const int pk2 = p0 + 32 + lc, pk3 = p0 + 48 + lc;
  const short* b0p = bb + (size_t)((pk0 >> 5) * 128 + (pk0 & 31) * 2) * 256;
  const short* b1p = bb + (size_t)((pk1 >> 5) * 128 + (pk1 & 31) * 2) * 256;
  const short* b2p = bb + (size_t)((pk2 >> 5) * 128 + (pk2 & 31) * 2) * 256;
  const short* b3p = bb + (size_t)((pk3 >> 5) * 128 + (pk3 & 31) * 2) * 256;
  f32x4 acc0 = {0.f, 0.f, 0.f, 0.f};
  f32x4 acc1 = {0.f, 0.f, 0.f, 0.f};
  f32x4 acc2 = {0.f, 0.f, 0.f, 0.f};
  f32x4 acc3 = {0.f, 0.f, 0.f, 0.f};
#pragma unroll
  for (int kt = 0; kt < 8; ++kt) {
    const short8 af = *reinterpret_cast<const short8*>(ar + kt * 32);
    acc0 = __builtin_amdgcn_mfma_f32_16x16x32_bf16(
        af, *reinterpret_cast<const short8*>(b0p + kt * 32), acc0, 0, 0, 0);
    acc1 = __builtin_amdgcn_mfma_f32_16x16x32_bf16(
        af, *reinterpret_cast<const short8*>(b1p + kt * 32), acc1, 0, 0, 0);
    acc2 = __builtin_amdgcn_mfma_f32_16x16x32_bf16(
        af, *reinterpret_cast<const short8*>(b2p + kt * 32), acc2, 0, 0, 0);
    acc3 = __builtin_amdgcn_mfma_f32_16x16x32_bf16(
        af, *reinterpret_cast<const short8*>(b3p + kt * 32), acc3, 0, 0, 0);
  }
#pragma unroll
  for (int r = 0; r < 4; ++r) {
    const int o = o0 + wv * 16 + 4 * lq + r;
    const int head = o >> 5, dd = o & 31;
    const float a_[4] = {acc0[r], acc1[r], acc2[r], acc3[r]};
#pragma unroll
    for (int nf = 0; nf < 4; ++nf) {
      const int p = p0 + 16 * nf + lc;
      if (!isV) {
        k_lb[((size_t)(n * 8 + head) * PKV + p) * 32 + dd] =
            __float2bfloat16(a_[nf]);
      } else {
        v_t[((size_t)(n * 8 + head) * 32 + dd) * PKV + p] =
            __float2bfloat16(a_[nf]);
      }
    }
  }
}

// ---------------------------------------------------------------------------
// Positional energy tables via MFMA (R10-proven, unchanged).
// ---------------------------------------------------------------------------
template <int MODE>
__global__ __launch_bounds__(256) void exy_kernel(
    const __hip_bfloat16* __restrict__ qgb_b,
    const __hip_bfloat16* __restrict__ pemb_b, float* __restrict__ OUT) {
  const int i = blockIdx.x;       // x (MODE0) or y (MODE1)
  const int g = blockIdx.y;
  const int head = g & 7;
  const int wv = threadIdx.x >> 6;
  const int l = threadIdx.x & 63;
  const int lc = l & 15, lq = l >> 4;

  const int rowi = wv * 16 + lc;  // y (MODE0) or x (MODE1)
  const int p = (MODE == 0) ? rowi * 64 + i : i * 64 + rowi;
  const short8 a = *reinterpret_cast<const short8*>(
      (const short*)qgb_b + ((size_t)g * PQ + p) * 32 + 8 * lq);

  int drow0, drow1;
  if (MODE == 0) {
    drow0 = i - 2 * lc + 62;
    drow1 = i - 2 * (lc + 16) + 62;
  } else {
    const int lo_y = max((i - 16) >> 1, 0);
    drow0 = i - 2 * (lo_y + lc) + 62;
    drow1 = i - 2 * (lo_y + lc + 16) + 62;
  }
  const short8 b0 = *reinterpret_cast<const short8*>(
      (const short*)pemb_b + (size_t)drow0 * 256 + head * 32 + 8 * lq);
  const short8 b1 = *reinterpret_cast<const short8*>(
      (const short*)pemb_b + (size_t)drow1 * 256 + head * 32 + 8 * lq);

  const f32x4 zero = {0.f, 0.f, 0.f, 0.f};
  const f32x4 c0 = __builtin_amdgcn_mfma_f32_16x16x32_bf16(a, b0, zero, 0, 0, 0);
  const f32x4 c1 = __builtin_amdgcn_mfma_f32_16x16x32_bf16(a, b1, zero, 0, 0, 0);

#pragma unroll
  for (int r = 0; r < 4; ++r) {
    const int rowr = wv * 16 + 4 * lq + r;
    const int pr = (MODE == 0) ? rowr * 64 + i : i * 64 + rowr;
    if (MODE == 0) {
      const int lox = max((i - 16) >> 1, 0);
      const int hix = min(((i + 17) >> 1) + 1, 32);
      float* o = OUT + ((size_t)g * PQ + pr) * EXSTRIDE;
      o[lc] = (lc >= lox && lc < hix) ? (c0[r] - M0) : -1e30f;
      o[16 + lc] = (lc + 16 >= lox && lc + 16 < hix) ? (c1[r] - M0) : -1e30f;
      if (lc < 4) o[32 + lc] = -1e30f;
    } else {
      float* o = OUT + ((size_t)g * PQ + pr) * EYSTRIDE;
      o[lc] = c0[r];
      if (lc < 4) o[16 + lc] = c1[r];
    }
  }
}

// ---------------------------------------------------------------------------
// MFMA local-window attention (R10-proven, unchanged; fp32 att store).
// ---------------------------------------------------------------------------
__global__ __launch_bounds__(256) void attn_mfma_kernel(
    const __hip_bfloat16* __restrict__ qab_b,
    const __hip_bfloat16* __restrict__ k_lb,
    const __hip_bfloat16* __restrict__ v_t, const float* __restrict__ EX,
    const float* __restrict__ EY, float* __restrict__ att) {
  const int g = blockIdx.y;    // n*8 + head
  const int bx = blockIdx.x & 3;   // x-tile of 16
  const int by = blockIdx.x >> 2;  // y-tile of 4 rows
  const int tx = bx * 16;
  const int wv = threadIdx.x >> 6;
  const int y = by * 4 + wv;
  const int l = threadIdx.x & 63;
  const int lc = l & 15;   // col lane (q for S^T / vd for O)
  const int lq = l >> 4;   // quarter

  __shared__ float eybuf[4][EYSTRIDE][16];  // [wave][t][q]

  const int KLO = max((tx - 16) >> 1, 0);
  const int lo_y = max((y - 16) >> 1, 0);
  const int hi_y = min(((y + 17) >> 1) + 1, 32);
  const int NKY = hi_y - lo_y;

  const int xq = tx + lc;
  const int pq_ = y * 64 + xq;

  // Qa B-frag: lane holds Qa[d=8lq+j][q=lc]
  const short8 qa = *reinterpret_cast<const short8*>(
      (const short*)qab_b + ((size_t)g * PQ + pq_) * 32 + 8 * lq);

  // per-lane loop-invariant ex registers (mask, M0, x-positional term baked)
  const float* exr = EX + ((size_t)g * PQ + pq_) * EXSTRIDE;
  float exC0[4], exC1[4];
#pragma unroll
  for (int r = 0; r < 4; ++r) {
    exC0[r] = exr[KLO + 4 * lq + r];
    exC1[r] = exr[min(KLO + 16 + 4 * lq + r, 35)];
  }

  // ey -> LDS ([t][q] layout for conflict-free loop reads)
  {
    const float* eyr = EY + ((size_t)g * PQ + pq_) * EYSTRIDE;
    const float4 e4 = *reinterpret_cast<const float4*>(eyr + 4 * lq);
#pragma unroll
    for (int j = 0; j < 4; ++j) eybuf[wv][4 * lq + j][lc] = e4[j];
    if (lq == 0) {
      const float4 e4b = *reinterpret_cast<const float4*>(eyr + 16);
#pragma unroll
      for (int j = 0; j < 4; ++j) eybuf[wv][16 + j][lc] = e4b[j];
    }
  }

  const __hip_bfloat16* kb =
      k_lb + ((size_t)g * PKV + (size_t)lo_y * 32) * 32;
  const __hip_bfloat16* kb0 = kb + (KLO + lc) * 32 + 8 * lq;
  const __hip_bfloat16* kb1 = kb + min(KLO + 16 + lc, 31) * 32 + 8 * lq;
  const __hip_bfloat16* vb0 =
      v_t + ((size_t)g * 32 + lc) * PKV + (size_t)lo_y * 32 + KLO + 8 * lq;
  const __hip_bfloat16* vb1 = vb0 + 16 * PKV;

  f32x4 acc0 = {0.f, 0.f, 0.f, 0.f};
  f32x4 acc1 = {0.f, 0.f, 0.f, 0.f};
  float lp = 0.f;
  const int srcA = lc + ((l & 16) << 1);  // lane lc + 32*(lq&1)
  const int srcB = srcA + 16;
  const bool hiL = (l & 32) != 0;

#pragma unroll 1
  for (int t = 0; t < NKY; ++t) {
    const short8 k0 = *reinterpret_cast<const short8*>(kb0 + t * 1024);
    const short8 k1 = *reinterpret_cast<const short8*>(kb1 + t * 1024);
    const short8 v0 = *reinterpret_cast<const short8*>(vb0 + t * 32);
    const short8 v1 = *reinterpret_cast<const short8*>(vb1 + t * 32);
    const f32x4 zero = {0.f, 0.f, 0.f, 0.f};
    // S^T tiles: rows kx_local = 4*lq + r, cols q = lc
    const f32x4 s0 = __builtin_amdgcn_mfma_f32_16x16x32_bf16(k0, qa, zero, 0, 0, 0);
    const f32x4 s1 = __builtin_amdgcn_mfma_f32_16x16x32_bf16(k1, qa, zero, 0, 0, 0);
    const float eyC = eybuf[wv][t][lc];
    float p0[4], p1[4];
#pragma unroll
    for (int r = 0; r < 4; ++r) {
      p0[r] = __expf(s0[r] + exC0[r] + eyC);   // masked: exC=-1e30 -> 0
      p1[r] = __expf(s1[r] + exC1[r] + eyC);
    }
    lp += ((p0[0] + p0[1]) + (p0[2] + p0[3])) +
          ((p1[0] + p1[1]) + (p1[2] + p1[3]));
    int w00, w01, w10, w11;
    asm("v_cvt_pk_bf16_f32 %0, %1, %2" : "=v"(w00) : "v"(p0[0]), "v"(p0[1]));
    asm("v_cvt_pk_bf16_f32 %0, %1, %2" : "=v"(w01) : "v"(p0[2]), "v"(p0[3]));
    asm("v_cvt_pk_bf16_f32 %0, %1, %2" : "=v"(w10) : "v"(p1[0]), "v"(p1[1]));
    asm("v_cvt_pk_bf16_f32 %0, %1, %2" : "=v"(w11) : "v"(p1[2]), "v"(p1[3]));
    const int a0 = __shfl(w00, srcA, 64), b0 = __shfl(w10, srcA, 64);
    const int a1 = __shfl(w01, srcA, 64), b1 = __shfl(w11, srcA, 64);
    const int a2 = __shfl(w00, srcB, 64), b2 = __shfl(w10, srcB, 64);
    const int a3 = __shfl(w01, srcB, 64), b3 = __shfl(w11, srcB, 64);
    int4 pw;
    pw.x = hiL ? b0 : a0;
    pw.y = hiL ? b1 : a1;
    pw.z = hiL ? b2 : a2;
    pw.w = hiL ? b3 : a3;
    const short8 pf = __builtin_bit_cast(short8, pw);
    acc0 = __builtin_amdgcn_mfma_f32_16x16x32_bf16(pf, v0, acc0, 0, 0, 0);
    acc1 = __builtin_amdgcn_mfma_f32_16x16x32_bf16(pf, v1, acc1, 0, 0, 0);
  }

  // l: sum over the 4 lq groups -> every lane holds L[q=lc]
  lp += __shfl_xor(lp, 16);
  lp += __shfl_xor(lp, 32);
  const float invall = 1.f / lp;
#pragma unroll
  for (int r = 0; r < 4; ++r) {
    const float inv = __shfl(invall, 4 * lq + r, 16);  // L for q = 4lq+r
    const int p = y * 64 + tx + 4 * lq + r;
    att[((size_t)g * 32 + lc) * PQ + p] = acc0[r] * inv;
    att[((size_t)g * 32 + 16 + lc) * PQ + p] = acc1[r] * inv;
  }
}

// ---------------------------------------------------------------------------
// att fp32 [g*32+vd][p] -> attb bf16 [n][p][c]  (R10-proven, unchanged)
// ---------------------------------------------------------------------------
__global__ __launch_bounds__(256) void att2b_kernel(
    const float* __restrict__ att, __hip_bfloat16* __restrict__ attb) {
  const int g = blockIdx.y;
  const int nImg = g >> 3, hd = g & 7;
  const int p0 = blockIdx.x * 64;
  const int tid = threadIdx.x;
  __shared__ float t[32][65];
  {
    const int pl = tid & 63;
    const int v0 = (tid >> 6) * 8;
#pragma unroll
    for (int j = 0; j < 8; ++j)
      t[v0 + j][pl] = att[((size_t)g * 32 + v0 + j) * PQ + p0 + pl];
  }
  __syncthreads();
  const int pl = tid & 63;
  const int vq = tid >> 6;
  short8 s;
#pragma unroll
  for (int j = 0; j < 8; ++j)
    s[j] = __builtin_bit_cast(short, __float2bfloat16(t[vq * 8 + j][pl]));
  *reinterpret_cast<short8*>(
      (short*)attb + ((size_t)nImg * PQ + p0 + pl) * 256 + hd * 32 + vq * 8) = s;
}

// ---------------------------------------------------------------------------
// MFMA GEMM: output projection + bias + gamma + residual (R10-proven).
// ---------------------------------------------------------------------------
__global__ __launch_bounds__(256) void gemm_out_kernel(
    const __hip_bfloat16* __restrict__ attb,
    const __hip_bfloat16* __restrict__ pw, const float* __restrict__ pb,
    const float* __restrict__ gamma, const float* __restrict__ x_in,
    float* __restrict__ out) {
  const int p0 = blockIdx.x * 64;
  const int o0 = blockIdx.y * 64;
  const int n = blockIdx.z;
  const int tid = threadIdx.x;
  const int wv = tid >> 6, l = tid & 63, lc = l & 15, lq = l >> 4;
  const short* ar =
      (const short*)pw + ((size_t)(o0 + wv * 16 + lc)) * 256 + 8 * lq;
  const short* bbase = (const short*)attb + ((size_t)n * PQ + p0) * 256 + 8 * lq;
  const short* b0p = bbase + (size_t)(0 + lc) * 256;
  const short* b1p = bbase + (size_t)(16 + lc) * 256;
  const short* b2p = bbase + (size_t)(32 + lc) * 256;
  const short* b3p = bbase + (size_t)(48 + lc) * 256;
  f32x4 acc0 = {0.f, 0.f, 0.f, 0.f};
  f32x4 acc1 = {0.f, 0.f, 0.f, 0.f};
  f32x4 acc2 = {0.f, 0.f, 0.f, 0.f};
  f32x4 acc3 = {0.f, 0.f, 0.f, 0.f};
#pragma unroll
  for (int kt = 0; kt < 8; ++kt) {
    const short8 af = *reinterpret_cast<const short8*>(ar + kt * 32);
    acc0 = __builtin_amdgcn_mfma_f32_16x16x32_bf16(
        af, *reinterpret_cast<const short8*>(b0p + kt * 32), acc0, 0, 0, 0);
    acc1 = __builtin_amdgcn_mfma_f32_16x16x32_bf16(
        af, *reinterpret_cast<const short8*>(b1p + kt * 32), acc1, 0, 0, 0);
    acc2 = __builtin_amdgcn_mfma_f32_16x16x32_bf16(
        af, *reinterpret_cast<const short8*>(b2p + kt * 32), acc2, 0, 0, 0);
    acc3 = __builtin_amdgcn_mfma_f32_16x16x32_bf16(
        af, *reinterpret_cast<const short8*>(b3p + kt * 32), acc3, 0, 0, 0);
  }
  const float gm = gamma[0];
#pragma unroll
  for (int r = 0; r < 4; ++r) {
    const int o = o0 + wv * 16 + 4 * lq + r;   // C row = 4*lq + r
    const float bo = pb[o];
    const size_t obase = ((size_t)n * 256 + o) * PQ;
    const size_t i0 = obase + (p0 + 0 + lc);
    const size_t i1 = obase + (p0 + 16 + lc);
    const size_t i2 = obase + (p0 + 32 + lc);
    const size_t i3 = obase + (p0 + 48 + lc);
    out[i0] = fmaf(gm, acc0[r] + bo, x_in[i0]);
    out[i1] = fmaf(gm, acc1[r] + bo, x_in[i1]);
    out[i2] = fmaf(gm, acc2[r] + bo, x_in[i2]);
    out[i3] = fmaf(gm, acc3[r] + bo, x_in[i3]);
  }
}

// ---------------------------------------------------------------------------
extern "C" void kernel_launch(void* const* d_in, const int* in_sizes, int n_in,
                              void* d_out, int out_size, void* d_ws,
                              size_t ws_size, hipStream_t stream) {
  const float* x = (const float*)d_in[0];
  const float* q_w = (const float*)d_in[1];
  const float* k_w = (const float*)d_in[2];
  const float* v_w = (const float*)d_in[3];
  const float* fcx_w = (const float*)d_in[4];
  const float* fcy_w = (const float*)d_in[5];
  const float* ab = (const float*)d_in[6];
  const float* gb = (const float*)d_in[7];
  const float* proj_w = (const float*)d_in[8];
  const float* proj_b = (const float*)d_in[9];
  const float* gamma = (const float*)d_in[10];
  float* out = (float*)d_out;

  float* ws = (float*)d_ws;
  float* att = ws;                       // 2,097,152 f
  float* EX = att + 2097152;             // 2,359,296 f
  float* EY = EX + 2359296;              // 1,310,720 f
  __hip_bfloat16* bp = (__hip_bfloat16*)(EY + 1310720);
  __hip_bfloat16* qab_b = bp;   bp += 2097152;
  __hip_bfloat16* qgb_b = bp;   bp += 2097152;
  __hip_bfloat16* k_lb = bp;    bp += 524288;
  __hip_bfloat16* v_t = bp;     bp += 524288;
  __hip_bfloat16* pembx_b = bp; bp += 32256;
  __hip_bfloat16* pemby_b = bp; bp += 32256;
  __hip_bfloat16* qw_b = bp;    bp += 65536;
  __hip_bfloat16* kw_b = bp;    bp += 65536;
  __hip_bfloat16* vw_b = bp;    bp += 65536;
  __hip_bfloat16* pw_b = bp;    bp += 65536;
  __hip_bfloat16* xb = bp;      bp += 2097152;
  __hip_bfloat16* attb = bp;    bp += 2097152;
  // total = 5,767,168 f + 9,763,840 bf16 = 42.6 MB (<= R10's proven 42.8)

  wconv4_kernel<<<dim3(64, 4), 256, 0, stream>>>(q_w, k_w, v_w, proj_w, qw_b,
                                                 kw_b, vw_b, pw_b);
  posfeat_kernel<<<dim3(126, 2), 256, 0, stream>>>(fcx_w, fcy_w, pembx_b,
                                                   pemby_b);
  xpose_kernel<<<dim3(64, 4, 2), 256, 0, stream>>>(x, xb);
  gemm_q_kernel<<<dim3(64, 4, 2), 256, 0, stream>>>(xb, qw_b, ab, gb, qab_b,
                                                    qgb_b);
  gemm_kv_kernel<<<dim3(16, 4, 4), 256, 0, stream>>>(xb, kw_b, vw_b, k_lb,
                                                     v_t);
  exy_kernel<0><<<dim3(64, 16), 256, 0, stream>>>(qgb_b, pembx_b, EX);
  exy_kernel<1><<<dim3(64, 16), 256, 0, stream>>>(qgb_b, pemby_b, EY);
  attn_mfma_kernel<<<dim3(64, 16), 256, 0, stream>>>(qab_b, k_lb, v_t, EX, EY,
                                                     att);
  att2b_kernel<<<dim3(64, 16), 256, 0, stream>>>(att, attb);
  gemm_out_kernel<<<dim3(64, 4, 2), 256, 0, stream>>>(attb, pw_b, proj_b,
                                                      gamma, x, out);
}